// Round 13
// baseline (202.566 us; speedup 1.0000x reference)
//
#include <hip/hip_runtime.h>
#include <hip/hip_bf16.h>
#include <math.h>

#define CDIM 384
#define NHEAD 8
#define HD 48
#define OUTD 32
#define MAXB 16
#define CONVK 10368  // 27*384

typedef __bf16 bf16x8 __attribute__((ext_vector_type(8)));
typedef float f32x4 __attribute__((ext_vector_type(4)));

__device__ __forceinline__ f32x4 mfma16(bf16x8 a, bf16x8 b, f32x4 c) {
  return __builtin_amdgcn_mfma_f32_16x16x32_bf16(a, b, c, 0, 0, 0);
}
__device__ __forceinline__ bf16x8 zero8() {
  bf16x8 z = {(__bf16)0.f, (__bf16)0.f, (__bf16)0.f, (__bf16)0.f,
              (__bf16)0.f, (__bf16)0.f, (__bf16)0.f, (__bf16)0.f};
  return z;
}

// ---- order-preserving float<->uint encoding for atomicMax segment max ----
__device__ __forceinline__ unsigned enc_f(float f) {
  unsigned u = __float_as_uint(f);
  return (u & 0x80000000u) ? ~u : (u | 0x80000000u);
}
__device__ __forceinline__ float dec_f(unsigned u) {
  unsigned v = (u & 0x80000000u) ? (u ^ 0x80000000u) : ~u;
  return __uint_as_float(v);
}

// tiny init: smin/smax sentinels + eb zeros
__global__ void init_small_kernel(int* smin, int* smax, int* eb) {
  int t = threadIdx.x;
  if (t < MAXB * 3) { smin[t] = 0x7fffffff; smax[t] = (int)0x80000000; }
  if (t <= MAXB) eb[t] = 0;
}

// fused one-shot prep: feats->bf16, 6x W^T, Wc^T, zero encA/encB, vt init,
// coord minmax, ebound. No hipMemsetAsync anywhere in the graph.
__global__ __launch_bounds__(256) void prep_kernel(
    const float* __restrict__ feats, __hip_bfloat16* __restrict__ feats16, int N,
    const float* __restrict__ W_pool, const float* __restrict__ W_emb,
    const float* __restrict__ Wk, const float* __restrict__ Wv,
    const float* __restrict__ Wq, const float* __restrict__ Wo,
    __hip_bfloat16* __restrict__ Wt_pe, __hip_bfloat16* __restrict__ Wt_kv,
    __hip_bfloat16* __restrict__ Wt_q, __hip_bfloat16* __restrict__ Wt_o,
    const float* __restrict__ Wc, __hip_bfloat16* __restrict__ Wct,
    unsigned* __restrict__ encA, unsigned* __restrict__ encB,
    __hip_bfloat16* __restrict__ vt, int Mepad,
    const int* __restrict__ ec, const int* __restrict__ pc, int Mp, int Me,
    const int* __restrict__ bsz, int* smin, int* smax, int* ebv,
    int nbF, int nbW, int nbC, int nbZA, int nbZB, int nbVt, int nbM) {
  __shared__ int lmin[MAXB * 3], lmax[MAXB * 3];
  int b = blockIdx.x;
  int t = threadIdx.x;
  if (b < nbF) {  // feats -> bf16
    int v = b * 256 + t;
    if (v < N * 48) {
      float4 a0 = *reinterpret_cast<const float4*>(feats + (size_t)v * 8);
      float4 a1 = *reinterpret_cast<const float4*>(feats + (size_t)v * 8 + 4);
      __hip_bfloat16 tmp[8] = {
        __float2bfloat16(a0.x), __float2bfloat16(a0.y), __float2bfloat16(a0.z), __float2bfloat16(a0.w),
        __float2bfloat16(a1.x), __float2bfloat16(a1.y), __float2bfloat16(a1.z), __float2bfloat16(a1.w)};
      *reinterpret_cast<bf16x8*>(feats16 + (size_t)v * 8) = *reinterpret_cast<const bf16x8*>(tmp);
    }
    return;
  }
  b -= nbF;
  if (b < 6 * nbW) {  // 384x384 weight transposes (coalesced reads)
    int m = b / nbW;
    int v = (b - m * nbW) * 256 + t;
    if (v >= CDIM * 48) return;
    const float* src;
    __hip_bfloat16* dst;
    switch (m) {
      case 0: src = W_pool; dst = Wt_pe; break;
      case 1: src = W_emb;  dst = Wt_pe + (size_t)CDIM * CDIM; break;
      case 2: src = Wk;     dst = Wt_kv; break;
      case 3: src = Wv;     dst = Wt_kv + (size_t)CDIM * CDIM; break;
      case 4: src = Wq;     dst = Wt_q; break;
      default: src = Wo;    dst = Wt_o; break;
    }
    int k8i = v / CDIM;
    int n = v - k8i * CDIM;        // fast -> coalesced
    int k8 = k8i * 8;
    __hip_bfloat16 tmp[8];
    #pragma unroll
    for (int u = 0; u < 8; ++u) tmp[u] = __float2bfloat16(src[(size_t)(k8 + u) * CDIM + n]);
    *reinterpret_cast<bf16x8*>(dst + (size_t)n * CDIM + k8) = *reinterpret_cast<const bf16x8*>(tmp);
    return;
  }
  b -= 6 * nbW;
  if (b < nbC) {  // Wc [10368][32] -> Wct [32][10368]
    int v = b * 256 + t;
    if (v >= OUTD * (CONVK / 8)) return;
    int k8i = v >> 5;
    int n = v & 31;
    int k8 = k8i * 8;
    __hip_bfloat16 tmp[8];
    #pragma unroll
    for (int u = 0; u < 8; ++u) tmp[u] = __float2bfloat16(Wc[(size_t)(k8 + u) * OUTD + n]);
    *reinterpret_cast<bf16x8*>(Wct + (size_t)n * CONVK + k8) = *reinterpret_cast<const bf16x8*>(tmp);
    return;
  }
  b -= nbC;
  if (b < nbZA) {  // zero encA (enc(-inf) floor), 16B/thread
    size_t v = (size_t)b * 256 + t;
    if (v < (size_t)Mp * 96) {
      uint4 z = {0u, 0u, 0u, 0u};
      reinterpret_cast<uint4*>(encA)[v] = z;
    }
    return;
  }
  b -= nbZA;
  if (b < nbZB) {  // zero encB
    size_t v = (size_t)b * 256 + t;
    if (v < (size_t)Me * 96) {
      uint4 z = {0u, 0u, 0u, 0u};
      reinterpret_cast<uint4*>(encB)[v] = z;
    }
    return;
  }
  b -= nbZB;
  if (b < nbVt) {  // vt init: 0 everywhere, 1.0 on d=48 row of each head
    int v = b * 256 + t;
    int g = Mepad >> 3;
    if (v < 512 * g) {
      int row = v / g;
      int c8 = (v - row * g) * 8;
      __hip_bfloat16 bv = __float2bfloat16(((row & 63) == HD) ? 1.0f : 0.0f);
      __hip_bfloat16 tmp[8] = {bv, bv, bv, bv, bv, bv, bv, bv};
      *reinterpret_cast<bf16x8*>(vt + (size_t)row * Mepad + c8) =
          *reinterpret_cast<const bf16x8*>(tmp);
    }
    return;
  }
  b -= nbVt;
  if (b < nbM) {  // per-batch coord min/max
    if (t < MAXB * 3) { lmin[t] = 0x7fffffff; lmax[t] = (int)0x80000000; }
    __syncthreads();
    int i = b * 256 + t;
    int tot = Me + Mp;
    if (i < tot) {
      const int* r = (i < Me) ? (ec + 4 * i) : (pc + 4 * (i - Me));
      int bb = r[0];
      #pragma unroll
      for (int d = 0; d < 3; ++d) {
        atomicMin(&lmin[bb * 3 + d], r[1 + d]);
        atomicMax(&lmax[bb * 3 + d], r[1 + d]);
      }
    }
    __syncthreads();
    if (t < MAXB * 3) {
      if (lmin[t] != 0x7fffffff) atomicMin(&smin[t], lmin[t]);
      if (lmax[t] != (int)0x80000000) atomicMax(&smax[t], lmax[t]);
    }
    return;
  }
  b -= nbM;
  {  // ebound
    int e = b * 256 + t;
    if (e == 0) { ebv[0] = 0; ebv[bsz[0]] = Me; }
    if (e > 0 && e < Me) {
      int b0 = ec[4 * (e - 1)], b1 = ec[4 * e];
      for (int bb = b0 + 1; bb <= b1; ++bb) ebv[bb] = e;
    }
  }
}

// decode segment-max, add sine PE (fast hw sin/cos), emit bf16 activations
__global__ void pe_kernel(const unsigned* __restrict__ encP, const unsigned* __restrict__ encE,
                          __hip_bfloat16* __restrict__ pool16, __hip_bfloat16* __restrict__ emb16,
                          const int* __restrict__ pc, int Mp,
                          const int* __restrict__ ec, int Me,
                          const int* __restrict__ smin, const int* __restrict__ smax) {
  int gid = blockIdx.x * blockDim.x + threadIdx.x;
  int total = (Mp + Me) * CDIM;
  if (gid >= total) return;
  int row = gid / CDIM, c = gid - row * CDIM;
  const int* coords;
  const unsigned* src;
  __hip_bfloat16* dst;
  int lrow;
  if (row < Me) { lrow = row; coords = ec + 4 * row; src = encE; dst = emb16; }
  else { lrow = row - Me; coords = pc + 4 * lrow; src = encP; dst = pool16; }
  int b = coords[0];
  int dim = c >> 7;
  int i = c & 127;
  int j = i >> 1;
  float x = (float)coords[1 + dim];
  float mn = (float)smin[b * 3 + dim];
  float mx = (float)smax[b * 3 + dim];
  float nrm = (x - mn) / (mx - mn + 1e-6f);
  float freq = exp2f(-(float)j * 0.20762050593046014f);  // 10000^(-j/64)
  float arg = nrm * 6.283185307179586f * freq;
  float pe = (i & 1) ? __cosf(arg) : __sinf(arg);
  float val = dec_f(src[(size_t)lrow * CDIM + c]) + pe;
  dst[(size_t)lrow * CDIM + c] = __float2bfloat16(val);
}

// Unified bf16 MFMA GEMM body (round-10 geometry: BM=128 x BN=64, measured
// best). EPI3 K-output now writes the fragment-friendly head-major layout
// kf[h][Mepad][64] (barrier-free attention reads fragments straight from L2).
template <int EPI>
__device__ __forceinline__ void mgemm_body(
    int bx, int by,
    __hip_bfloat16 (*As)[72], __hip_bfloat16 (*Bs)[72],
    const __hip_bfloat16* __restrict__ A, int M,
    const __hip_bfloat16* __restrict__ Wt,
    const float* __restrict__ bias0, const float* __restrict__ bias1,
    void* __restrict__ d0, void* __restrict__ d1,
    const int* __restrict__ inv0, const int* __restrict__ inv1,
    int Mepad) {
  const int m0 = bx * 128;
  const int n0 = by * 64;
  const int t = threadIdx.x;
  const int lane = t & 63, w = t >> 6;
  const int wr = w >> 1, wc = w & 1;
  const int lq = lane & 15, lg = lane >> 4;

  f32x4 acc[4][2];
  #pragma unroll
  for (int i = 0; i < 4; ++i) {
    acc[i][0] = (f32x4){0.f, 0.f, 0.f, 0.f};
    acc[i][1] = (f32x4){0.f, 0.f, 0.f, 0.f};
  }
  const int arow = t >> 3;
  const int acol = (t & 7) * 8;

  for (int k0 = 0; k0 < CDIM; k0 += 64) {
    #pragma unroll
    for (int i = 0; i < 4; ++i) {
      int r = arow + i * 32;
      int gr = m0 + r;
      bf16x8 val = zero8();
      if (gr < M) val = *reinterpret_cast<const bf16x8*>(A + (size_t)gr * CDIM + k0 + acol);
      *reinterpret_cast<bf16x8*>(&As[r][acol]) = val;
    }
    #pragma unroll
    for (int i = 0; i < 2; ++i) {
      int r = arow + i * 32;
      bf16x8 val = *reinterpret_cast<const bf16x8*>(Wt + (size_t)(n0 + r) * CDIM + k0 + acol);
      *reinterpret_cast<bf16x8*>(&Bs[r][acol]) = val;
    }
    __syncthreads();
    #pragma unroll
    for (int ks = 0; ks < 2; ++ks) {
      bf16x8 af[4], bfv[2];
      #pragma unroll
      for (int fm = 0; fm < 4; ++fm)
        af[fm] = *reinterpret_cast<const bf16x8*>(&As[wr * 64 + fm * 16 + lq][ks * 32 + lg * 8]);
      #pragma unroll
      for (int fn = 0; fn < 2; ++fn)
        bfv[fn] = *reinterpret_cast<const bf16x8*>(&Bs[wc * 32 + fn * 16 + lq][ks * 32 + lg * 8]);
      #pragma unroll
      for (int fm = 0; fm < 4; ++fm)
        #pragma unroll
        for (int fn = 0; fn < 2; ++fn)
          acc[fm][fn] = mfma16(af[fm], bfv[fn], acc[fm][fn]);
    }
    __syncthreads();
  }

  const bool sec = (n0 >= CDIM);
  const int nb = n0 - (sec ? CDIM : 0) + wc * 32;
  const int nA = nb + lq, nB = nb + 16 + lq;

  if (EPI == 0) {
    const float* bias = sec ? bias1 : bias0;
    unsigned* dst = (unsigned*)(sec ? d1 : d0);
    const int* inv = sec ? inv1 : inv0;
    float bA = bias[nA], bB = bias[nB];
    #pragma unroll
    for (int fm = 0; fm < 4; ++fm) {
      int rbase = m0 + wr * 64 + fm * 16 + lg * 4;
      int cs = -1;
      float mA = 0.f, mB = 0.f;
      #pragma unroll
      for (int j = 0; j < 4; ++j) {
        int r = rbase + j;
        if (r < M) {
          int s = inv[r];
          float vA = acc[fm][0][j] + bA;
          float vB = acc[fm][1][j] + bB;
          if (s == cs) { mA = fmaxf(mA, vA); mB = fmaxf(mB, vB); }
          else {
            if (cs >= 0) {
              atomicMax(&dst[(size_t)cs * CDIM + nA], enc_f(mA));
              atomicMax(&dst[(size_t)cs * CDIM + nB], enc_f(mB));
            }
            cs = s; mA = vA; mB = vB;
          }
        }
      }
      if (cs >= 0) {
        atomicMax(&dst[(size_t)cs * CDIM + nA], enc_f(mA));
        atomicMax(&dst[(size_t)cs * CDIM + nB], enc_f(mB));
      }
    }
  } else if (EPI == 1) {
    float bA = bias0[nA], bB = bias0[nB];
    float* dst = (float*)d0;
    #pragma unroll
    for (int fm = 0; fm < 4; ++fm)
      #pragma unroll
      for (int j = 0; j < 4; ++j) {
        int r = m0 + wr * 64 + fm * 16 + lg * 4 + j;
        if (r < M) {
          dst[(size_t)r * CDIM + nA] = acc[fm][0][j] + bA;
          dst[(size_t)r * CDIM + nB] = acc[fm][1][j] + bB;
        }
      }
  } else if (EPI == 2) {
    // scale = log2(e)/sqrt(48): softmax via exp2 (exact rewrite)
    const float scale = 0.2082350914f;
    float bA = bias0[nA], bB = bias0[nB];
    int hA = nA / HD, dA = nA - hA * HD;
    int hB = nB / HD, dB = nB - hB * HD;
    __hip_bfloat16* dst = (__hip_bfloat16*)d0;
    #pragma unroll
    for (int fm = 0; fm < 4; ++fm)
      #pragma unroll
      for (int j = 0; j < 4; ++j) {
        int r = m0 + wr * 64 + fm * 16 + lg * 4 + j;
        if (r < M) {
          dst[(size_t)r * 512 + hA * 64 + dA] = __float2bfloat16((acc[fm][0][j] + bA) * scale);
          dst[(size_t)r * 512 + hB * 64 + dB] = __float2bfloat16((acc[fm][1][j] + bB) * scale);
        }
      }
  } else {  // EPI 3: K -> kf[h][Mepad][64] (fragment layout); V -> vt transposed
    if (!sec) {
      float bA = bias0[nA], bB = bias0[nB];
      int hA = nA / HD, dA = nA - hA * HD;
      int hB = nB / HD, dB = nB - hB * HD;
      __hip_bfloat16* dst = (__hip_bfloat16*)d0;
      #pragma unroll
      for (int fm = 0; fm < 4; ++fm)
        #pragma unroll
        for (int j = 0; j < 4; ++j) {
          int r = m0 + wr * 64 + fm * 16 + lg * 4 + j;
          if (r < M) {
            dst[((size_t)hA * Mepad + r) * 64 + dA] = __float2bfloat16(acc[fm][0][j] + bA);
            dst[((size_t)hB * Mepad + r) * 64 + dB] = __float2bfloat16(acc[fm][1][j] + bB);
          }
        }
    } else {
      float bA = bias1[nA], bB = bias1[nB];
      int hA = nA / HD, dA = nA - hA * HD;
      int hB = nB / HD, dB = nB - hB * HD;
      __hip_bfloat16* dst = (__hip_bfloat16*)d1;
      #pragma unroll
      for (int fm = 0; fm < 4; ++fm)
        #pragma unroll
        for (int j = 0; j < 4; ++j) {
          int r = m0 + wr * 64 + fm * 16 + lg * 4 + j;
          if (r < M) {
            dst[(size_t)(hA * 64 + dA) * Mepad + r] = __float2bfloat16(acc[fm][0][j] + bA);
            dst[(size_t)(hB * 64 + dB) * Mepad + r] = __float2bfloat16(acc[fm][1][j] + bB);
          }
        }
    }
  }
  // pad-zero head lanes d=48..63 (disjoint from data lanes; prevents stale
  // enc bits reaching unmasked MFMA as NaN).
  if (EPI == 2 && n0 == 0) {
    __hip_bfloat16* dst = (__hip_bfloat16*)d0;   // q16 [M][512]
    for (int c = t; c < 1024; c += 256) {
      int r = m0 + (c >> 3);
      int hx = c & 7;
      if (r < M) {
        bf16x8 z = zero8();
        *reinterpret_cast<bf16x8*>(dst + (size_t)r * 512 + hx * 64 + 48) = z;
        *reinterpret_cast<bf16x8*>(dst + (size_t)r * 512 + hx * 64 + 56) = z;
      }
    }
  }
  if (EPI == 3 && n0 == 0) {
    __hip_bfloat16* dst = (__hip_bfloat16*)d0;   // kf [8][Mepad][64]
    for (int c = t; c < 1024; c += 256) {
      int r = m0 + (c >> 3);
      int hx = c & 7;
      if (r < M) {
        bf16x8 z = zero8();
        *reinterpret_cast<bf16x8*>(dst + ((size_t)hx * Mepad + r) * 64 + 48) = z;
        *reinterpret_cast<bf16x8*>(dst + ((size_t)hx * Mepad + r) * 64 + 56) = z;
      }
    }
  }
}

__global__ __launch_bounds__(256) void mgemm0_kernel(
    const __hip_bfloat16* __restrict__ A, int M, const __hip_bfloat16* __restrict__ Wt,
    const float* __restrict__ bias0, const float* __restrict__ bias1,
    unsigned* __restrict__ d0, unsigned* __restrict__ d1,
    const int* __restrict__ inv0, const int* __restrict__ inv1) {
  __shared__ __align__(16) __hip_bfloat16 As[128][72];
  __shared__ __align__(16) __hip_bfloat16 Bs[64][72];
  mgemm_body<0>(blockIdx.x, blockIdx.y, As, Bs, A, M, Wt, bias0, bias1, d0, d1, inv0, inv1, 0);
}

__global__ __launch_bounds__(256) void mgemm1_kernel(
    const __hip_bfloat16* __restrict__ A, int M, const __hip_bfloat16* __restrict__ Wt,
    const float* __restrict__ bias0, float* __restrict__ d0) {
  __shared__ __align__(16) __hip_bfloat16 As[128][72];
  __shared__ __align__(16) __hip_bfloat16 Bs[64][72];
  mgemm_body<1>(blockIdx.x, blockIdx.y, As, Bs, A, M, Wt, bias0, nullptr, d0, nullptr, nullptr, nullptr, 0);
}

// horizontally fused q-projection (EPI2) + kv-projection (EPI3)
__global__ __launch_bounds__(256) void qkv_kernel(
    const __hip_bfloat16* __restrict__ pool16, int Mp, const __hip_bfloat16* __restrict__ Wt_q,
    const float* __restrict__ bq,
    const __hip_bfloat16* __restrict__ emb16, int Me, const __hip_bfloat16* __restrict__ Wt_kv,
    const float* __restrict__ bk, const float* __restrict__ bv,
    __hip_bfloat16* __restrict__ q16, __hip_bfloat16* __restrict__ kf,
    __hip_bfloat16* __restrict__ vt, int Mepad, int nbQ, int gxQ, int gxK) {
  __shared__ __align__(16) __hip_bfloat16 As[128][72];
  __shared__ __align__(16) __hip_bfloat16 Bs[64][72];
  int b = blockIdx.x;
  if (b < nbQ) {
    mgemm_body<2>(b % gxQ, b / gxQ, As, Bs, pool16, Mp, Wt_q, bq, nullptr,
                  q16, nullptr, nullptr, nullptr, Mepad);
  } else {
    b -= nbQ;
    mgemm_body<3>(b % gxK, b / gxK, As, Bs, emb16, Me, Wt_kv, bk, bv,
                  kf, vt, nullptr, nullptr, Mepad);
  }
}

// MFMA flash attention, round 13: BARRIER-FREE main loop.
// K stored fragment-friendly kf[h][Mepad][64]; V^T vt[h*64+d][Mepad]. Waves
// read B-fragments straight from L2 (coalesced 2KB regions) — no K/V LDS
// staging, so the ONLY LDS use is the wave-local P buffer and there are zero
// __syncthreads in the loop. Waves run fully independently (latency hidden
// by TLP), each over its own 16-query e-range.
__global__ __launch_bounds__(256) void attn_mfma_kernel(
    const __hip_bfloat16* __restrict__ qb, const __hip_bfloat16* __restrict__ kf,
    const __hip_bfloat16* __restrict__ vt, int Mepad,
    const int* __restrict__ pc, const int* __restrict__ eb,
    int Mp, int Me, __hip_bfloat16* __restrict__ ob) {
  __shared__ __align__(16) __hip_bfloat16 pl[4][16][72];
  const int h = blockIdx.y;
  const int t = threadIdx.x;
  const int wv = t >> 6, lane = t & 63;
  const int lq = lane & 15, lg = lane >> 4;
  const int q0 = blockIdx.x * 64 + wv * 16;

  int lo[4], hi[4];
  #pragma unroll
  for (int r = 0; r < 4; ++r) {
    int q = q0 + lg * 4 + r;
    if (q < Mp) { int b = pc[4 * q]; lo[r] = eb[b]; hi[r] = eb[b + 1]; }
    else { lo[r] = 0x7fffffff; hi[r] = 0; }
  }
  // wave-local bounds (the wave's 16 queries) — shuffle only, no LDS/barrier
  int lomin = min(min(lo[0], lo[1]), min(lo[2], lo[3]));
  int lomax = max(max(lo[0], lo[1]), max(lo[2], lo[3]));
  int himin = min(min(hi[0], hi[1]), min(hi[2], hi[3]));
  int himax = max(max(hi[0], hi[1]), max(hi[2], hi[3]));
  #pragma unroll
  for (int off = 1; off < 64; off <<= 1) {
    lomin = min(lomin, __shfl_xor(lomin, off));
    lomax = max(lomax, __shfl_xor(lomax, off));
    himin = min(himin, __shfl_xor(himin, off));
    himax = max(himax, __shfl_xor(himax, off));
  }

  int qrow = min(q0 + lq, Mp - 1);
  const __hip_bfloat16* qp = qb + (size_t)qrow * 512 + h * 64 + lg * 8;
  bf16x8 aq0 = *reinterpret_cast<const bf16x8*>(qp);
  bf16x8 aq1 = *reinterpret_cast<const bf16x8*>(qp + 32);

  const __hip_bfloat16* kbase = kf + (size_t)h * Mepad * 64;
  const __hip_bfloat16* vbase = vt + (size_t)h * 64 * Mepad;

  f32x4 zero = {0.f, 0.f, 0.f, 0.f};
  f32x4 oacc[4];
  oacc[0] = zero; oacc[1] = zero; oacc[2] = zero; oacc[3] = zero;

  for (int e0 = (lomin & ~63); e0 < himax; e0 += 64) {
    // QK^T: B-fragments straight from global (L2-resident, coalesced regions)
    f32x4 sf[4];
    #pragma unroll
    for (int s = 0; s < 4; ++s) {
      const __hip_bfloat16* kp = kbase + (size_t)(e0 + s * 16 + lq) * 64 + lg * 8;
      bf16x8 bk0 = *reinterpret_cast<const bf16x8*>(kp);
      bf16x8 bk1 = *reinterpret_cast<const bf16x8*>(kp + 32);
      f32x4 z = zero;
      z = mfma16(aq0, bk0, z);
      z = mfma16(aq1, bk1, z);
      sf[s] = z;
    }
    const bool interior = (e0 >= lomax) && (e0 + 64 <= himin);
    if (interior) {
      #pragma unroll
      for (int s = 0; s < 4; ++s)
        #pragma unroll
        for (int r = 0; r < 4; ++r)
          pl[wv][lg * 4 + r][s * 16 + lq] = __float2bfloat16(exp2f(sf[s][r]));
    } else {
      #pragma unroll
      for (int s = 0; s < 4; ++s) {
        int e = e0 + s * 16 + lq;
        #pragma unroll
        for (int r = 0; r < 4; ++r) {
          bool m = (e >= lo[r]) && (e < hi[r]);
          float p = m ? exp2f(sf[s][r]) : 0.f;
          pl[wv][lg * 4 + r][s * 16 + lq] = __float2bfloat16(p);
        }
      }
    }
    asm volatile("s_waitcnt lgkmcnt(0)" ::: "memory");
    __builtin_amdgcn_sched_barrier(0);  // rule #18 (wave-local LDS ordering)
    #pragma unroll
    for (int ks = 0; ks < 2; ++ks) {
      bf16x8 ap = *reinterpret_cast<const bf16x8*>(&pl[wv][lq][ks * 32 + lg * 8]);
      #pragma unroll
      for (int dt = 0; dt < 4; ++dt) {
        const __hip_bfloat16* vp = vbase + (size_t)(dt * 16 + lq) * Mepad + e0 + ks * 32 + lg * 8;
        bf16x8 bv = *reinterpret_cast<const bf16x8*>(vp);
        oacc[dt] = mfma16(ap, bv, oacc[dt]);
      }
    }
  }

  #pragma unroll
  for (int r = 0; r < 4; ++r) {
    float l = __shfl(oacc[3][r], (lane & 48));
    int q = q0 + lg * 4 + r;
    if (q < Mp && l > 0.f) {
      float inv = 1.0f / l;
      __hip_bfloat16* op = ob + (size_t)q * CDIM + h * HD;
      op[lq]      = __float2bfloat16(oacc[0][r] * inv);
      op[16 + lq] = __float2bfloat16(oacc[1][r] * inv);
      op[32 + lq] = __float2bfloat16(oacc[2][r] * inv);
    }
  }
}

__global__ void newf16_kernel(const float* __restrict__ feats, const float* __restrict__ o2,
                              const int* __restrict__ pinv, __hip_bfloat16* __restrict__ nf,
                              int N) {
  int v = blockIdx.x * 256 + threadIdx.x;
  if (v >= N * 48) return;
  int n = v / 48, c8 = (v - n * 48) * 8;
  const float* fp = feats + (size_t)n * CDIM + c8;
  const float* op = o2 + (size_t)pinv[n] * CDIM + c8;
  float4 a0 = *reinterpret_cast<const float4*>(fp);
  float4 a1 = *reinterpret_cast<const float4*>(fp + 4);
  float4 b0 = *reinterpret_cast<const float4*>(op);
  float4 b1 = *reinterpret_cast<const float4*>(op + 4);
  __hip_bfloat16 tmp[8] = {
    __float2bfloat16(a0.x + b0.x), __float2bfloat16(a0.y + b0.y),
    __float2bfloat16(a0.z + b0.z), __float2bfloat16(a0.w + b0.w),
    __float2bfloat16(a1.x + b1.x), __float2bfloat16(a1.y + b1.y),
    __float2bfloat16(a1.z + b1.z), __float2bfloat16(a1.w + b1.w)};
  *reinterpret_cast<bf16x8*>(nf + (size_t)v * 8) = *reinterpret_cast<const bf16x8*>(tmp);
}

// conv as MFMA GEMM: M=N rows, 32 cols, K split by tap groups (9 x 3 taps).
__global__ __launch_bounds__(256) void mconv_kernel(
    const __hip_bfloat16* __restrict__ nf, const int* __restrict__ nbr,
    const __hip_bfloat16* __restrict__ Wct, float* __restrict__ outp, int N) {
  __shared__ __align__(16) __hip_bfloat16 As[128][72];
  __shared__ __align__(16) __hip_bfloat16 Bs[32][72];
  __shared__ int jrow[128];
  const int n0 = blockIdx.x * 128;
  const int kg = blockIdx.y;
  const int t = threadIdx.x;
  const int lane = t & 63, w = t >> 6;
  const int lq = lane & 15, lg = lane >> 4;
  f32x4 acc[2][2];
  acc[0][0] = (f32x4){0.f,0.f,0.f,0.f}; acc[0][1] = acc[0][0];
  acc[1][0] = acc[0][0]; acc[1][1] = acc[0][0];
  const int arow = t >> 3, acol = (t & 7) * 8;

  for (int kk = kg * 3; kk < kg * 3 + 3; ++kk) {
    __syncthreads();
    if (t < 128) {
      int n = n0 + t;
      jrow[t] = (n < N) ? nbr[(size_t)n * 27 + kk] : -1;
    }
    __syncthreads();
    for (int c0 = 0; c0 < CDIM; c0 += 64) {
      #pragma unroll
      for (int i = 0; i < 4; ++i) {
        int r = arow + i * 32;
        int j = jrow[r];
        bf16x8 val = zero8();
        if (j >= 0) val = *reinterpret_cast<const bf16x8*>(nf + (size_t)j * CDIM + c0 + acol);
        *reinterpret_cast<bf16x8*>(&As[r][acol]) = val;
      }
      {
        int r = t >> 3;
        bf16x8 val = *reinterpret_cast<const bf16x8*>(Wct + (size_t)r * CONVK + kk * CDIM + c0 + acol);
        *reinterpret_cast<bf16x8*>(&Bs[r][acol]) = val;
      }
      __syncthreads();
      #pragma unroll
      for (int ks = 0; ks < 2; ++ks) {
        bf16x8 af[2], bfv[2];
        #pragma unroll
        for (int fm = 0; fm < 2; ++fm)
          af[fm] = *reinterpret_cast<const bf16x8*>(&As[w * 32 + fm * 16 + lq][ks * 32 + lg * 8]);
        #pragma unroll
        for (int fn = 0; fn < 2; ++fn)
          bfv[fn] = *reinterpret_cast<const bf16x8*>(&Bs[fn * 16 + lq][ks * 32 + lg * 8]);
        #pragma unroll
        for (int fm = 0; fm < 2; ++fm)
          #pragma unroll
          for (int fn = 0; fn < 2; ++fn)
            acc[fm][fn] = mfma16(af[fm], bfv[fn], acc[fm][fn]);
      }
      __syncthreads();
    }
  }
  #pragma unroll
  for (int fm = 0; fm < 2; ++fm)
    #pragma unroll
    for (int j = 0; j < 4; ++j) {
      int r = n0 + w * 32 + fm * 16 + lg * 4 + j;
      if (r < N) {
        #pragma unroll
        for (int fn = 0; fn < 2; ++fn)
          outp[((size_t)kg * N + r) * OUTD + fn * 16 + lq] = acc[fm][fn][j];
      }
    }
}

__global__ void conv_reduce_kernel(const float* __restrict__ outp,
                                   const float* __restrict__ bc,
                                   float* __restrict__ out, int N) {
  int v = blockIdx.x * 256 + threadIdx.x;
  if (v >= N * OUTD) return;
  int oo = v & (OUTD - 1);
  float s = bc[oo];
  #pragma unroll
  for (int kg = 0; kg < 9; ++kg) s += outp[(size_t)kg * N * OUTD + v];
  out[v] = s;
}

extern "C" void kernel_launch(void* const* d_in, const int* in_sizes, int n_in,
                              void* d_out, int out_size, void* d_ws, size_t ws_size,
                              hipStream_t stream) {
  const float* feats  = (const float*)d_in[0];
  const float* W_pool = (const float*)d_in[1];
  const float* b_pool = (const float*)d_in[2];
  const float* W_emb  = (const float*)d_in[3];
  const float* b_emb  = (const float*)d_in[4];
  const float* Wq = (const float*)d_in[5];  const float* bq = (const float*)d_in[6];
  const float* Wk = (const float*)d_in[7];  const float* bk = (const float*)d_in[8];
  const float* Wv = (const float*)d_in[9];  const float* bv = (const float*)d_in[10];
  const float* Wo = (const float*)d_in[11]; const float* bo = (const float*)d_in[12];
  const float* Wc = (const float*)d_in[13]; const float* bc = (const float*)d_in[14];
  const int* pool_inv    = (const int*)d_in[15];
  const int* pool_coords = (const int*)d_in[16];
  const int* emb_inv     = (const int*)d_in[17];
  const int* emb_coords  = (const int*)d_in[18];
  const int* nbr         = (const int*)d_in[19];
  const int* bsz         = (const int*)d_in[20];
  int N  = in_sizes[0] / CDIM;
  int Mp = in_sizes[16] / 4;
  int Me = in_sizes[18] / 4;
  int Mepad = ((Me >> 6) + 2) << 6;

  char* wsb = (char*)d_ws;
  size_t off = 0;
  auto alloc = [&](size_t bytes) { void* p = wsb + off; off += (bytes + 255) & ~(size_t)255; return p; };
  unsigned* encA = (unsigned*)alloc((size_t)Mp * CDIM * 4);
  unsigned* encB = (unsigned*)alloc((size_t)Me * CDIM * 4);
  __hip_bfloat16* vt = (__hip_bfloat16*)alloc((size_t)512 * Mepad * 2);
  __hip_bfloat16* pool16  = (__hip_bfloat16*)alloc((size_t)Mp * CDIM * 2);
  __hip_bfloat16* emb16   = (__hip_bfloat16*)alloc((size_t)Me * CDIM * 2);
  __hip_bfloat16* feats16 = (__hip_bfloat16*)alloc((size_t)N * CDIM * 2);
  float* o2 = (float*)alloc((size_t)Mp * CDIM * 4 > (size_t)9 * N * OUTD * 4
                                ? (size_t)Mp * CDIM * 4 : (size_t)9 * N * OUTD * 4);
  __hip_bfloat16* Wt_pe = (__hip_bfloat16*)alloc((size_t)768 * CDIM * 2);
  __hip_bfloat16* Wt_kv = (__hip_bfloat16*)alloc((size_t)768 * CDIM * 2);
  __hip_bfloat16* Wt_q  = (__hip_bfloat16*)alloc((size_t)CDIM * CDIM * 2);
  __hip_bfloat16* Wt_o  = (__hip_bfloat16*)alloc((size_t)CDIM * CDIM * 2);
  __hip_bfloat16* Wct   = (__hip_bfloat16*)alloc((size_t)OUTD * CONVK * 2);
  int* smin = (int*)alloc(MAXB * 3 * 4);
  int* smax = (int*)alloc(MAXB * 3 * 4);
  int* eb   = (int*)alloc((MAXB + 1) * 4);

  __hip_bfloat16* q16 = (__hip_bfloat16*)encA;    // [Mp][512]
  __hip_bfloat16* kf  = (__hip_bfloat16*)encB;    // [8][Mepad][64] (1.2MB <= encB 1.5MB)
  __hip_bfloat16* ob16 = pool16;                  // [Mp][384]
  __hip_bfloat16* newf16 = feats16;               // [N][384]
  float* outp = o2;                               // [9][N][32]

  init_small_kernel<<<1, 64, 0, stream>>>(smin, smax, eb);

  int nbF  = (N * 48 + 255) / 256;
  int nbW  = (CDIM * 48 + 255) / 256;
  int nbC  = (OUTD * (CONVK / 8) + 255) / 256;
  int nbZA = ((Mp * 96) + 255) / 256;
  int nbZB = ((Me * 96) + 255) / 256;
  int nbVt = ((512 * (Mepad >> 3)) + 255) / 256;
  int nbM  = (Mp + Me + 255) / 256;
  int nbE  = (Me + 255) / 256;
  prep_kernel<<<nbF + 6 * nbW + nbC + nbZA + nbZB + nbVt + nbM + nbE, 256, 0, stream>>>(
      feats, feats16, N, W_pool, W_emb, Wk, Wv, Wq, Wo,
      Wt_pe, Wt_kv, Wt_q, Wt_o, Wc, Wct, encA, encB, vt, Mepad,
      emb_coords, pool_coords, Mp, Me, bsz, smin, smax, eb,
      nbF, nbW, nbC, nbZA, nbZB, nbVt, nbM);

  mgemm0_kernel<<<dim3((N + 127) / 128, 12), 256, 0, stream>>>(
      feats16, N, Wt_pe, b_pool, b_emb, encA, encB, pool_inv, emb_inv);
  pe_kernel<<<((Mp + Me) * CDIM + 255) / 256, 256, 0, stream>>>(
      encA, encB, pool16, emb16, pool_coords, Mp, emb_coords, Me, smin, smax);

  // fused q + kv projections (pads zeroed in-kernel; K in fragment layout)
  {
    int gxQ = (Mp + 127) / 128, gxK = (Me + 127) / 128;
    int nbQ = gxQ * 6;
    qkv_kernel<<<nbQ + gxK * 12, 256, 0, stream>>>(
        pool16, Mp, Wt_q, bq, emb16, Me, Wt_kv, bk, bv,
        q16, kf, vt, Mepad, nbQ, gxQ, gxK);
  }

  attn_mfma_kernel<<<dim3((Mp + 63) / 64, NHEAD), 256, 0, stream>>>(
      q16, kf, vt, Mepad, pool_coords, eb, Mp, Me, ob16);

  mgemm1_kernel<<<dim3((Mp + 127) / 128, 6), 256, 0, stream>>>(
      ob16, Mp, Wt_o, bo, o2);

  newf16_kernel<<<(N * 48 + 255) / 256, 256, 0, stream>>>(feats, o2, pool_inv, newf16, N);

  mconv_kernel<<<dim3((N + 127) / 128, 9), 256, 0, stream>>>(newf16, nbr, Wct, outp, N);
  conv_reduce_kernel<<<(N * OUTD + 255) / 256, 256, 0, stream>>>(outp, bc, (float*)d_out, N);
}

// Round 14
// 168.363 us; speedup vs baseline: 1.2032x; 1.2032x over previous
//
#include <hip/hip_runtime.h>
#include <hip/hip_bf16.h>
#include <math.h>

#define CDIM 384
#define NHEAD 8
#define HD 48
#define OUTD 32
#define MAXB 16
#define CONVK 10368  // 27*384

typedef __bf16 bf16x8 __attribute__((ext_vector_type(8)));
typedef float f32x4 __attribute__((ext_vector_type(4)));

__device__ __forceinline__ f32x4 mfma16(bf16x8 a, bf16x8 b, f32x4 c) {
  return __builtin_amdgcn_mfma_f32_16x16x32_bf16(a, b, c, 0, 0, 0);
}
__device__ __forceinline__ bf16x8 zero8() {
  bf16x8 z = {(__bf16)0.f, (__bf16)0.f, (__bf16)0.f, (__bf16)0.f,
              (__bf16)0.f, (__bf16)0.f, (__bf16)0.f, (__bf16)0.f};
  return z;
}

// ---- order-preserving float<->uint encoding for atomicMax segment max ----
__device__ __forceinline__ unsigned enc_f(float f) {
  unsigned u = __float_as_uint(f);
  return (u & 0x80000000u) ? ~u : (u | 0x80000000u);
}
__device__ __forceinline__ float dec_f(unsigned u) {
  unsigned v = (u & 0x80000000u) ? (u ^ 0x80000000u) : ~u;
  return __uint_as_float(v);
}

// tiny init: smin/smax sentinels + eb zeros
__global__ void init_small_kernel(int* smin, int* smax, int* eb) {
  int t = threadIdx.x;
  if (t < MAXB * 3) { smin[t] = 0x7fffffff; smax[t] = (int)0x80000000; }
  if (t <= MAXB) eb[t] = 0;
}

// fused one-shot prep: feats->bf16, 6x W^T, Wc^T, zero encA/encB, vt init,
// coord minmax, ebound. No hipMemsetAsync anywhere in the graph.
__global__ __launch_bounds__(256) void prep_kernel(
    const float* __restrict__ feats, __hip_bfloat16* __restrict__ feats16, int N,
    const float* __restrict__ W_pool, const float* __restrict__ W_emb,
    const float* __restrict__ Wk, const float* __restrict__ Wv,
    const float* __restrict__ Wq, const float* __restrict__ Wo,
    __hip_bfloat16* __restrict__ Wt_pe, __hip_bfloat16* __restrict__ Wt_kv,
    __hip_bfloat16* __restrict__ Wt_q, __hip_bfloat16* __restrict__ Wt_o,
    const float* __restrict__ Wc, __hip_bfloat16* __restrict__ Wct,
    unsigned* __restrict__ encA, unsigned* __restrict__ encB,
    __hip_bfloat16* __restrict__ vt, int Mepad,
    const int* __restrict__ ec, const int* __restrict__ pc, int Mp, int Me,
    const int* __restrict__ bsz, int* smin, int* smax, int* ebv,
    int nbF, int nbW, int nbC, int nbZA, int nbZB, int nbVt, int nbM) {
  __shared__ int lmin[MAXB * 3], lmax[MAXB * 3];
  int b = blockIdx.x;
  int t = threadIdx.x;
  if (b < nbF) {  // feats -> bf16
    int v = b * 256 + t;
    if (v < N * 48) {
      float4 a0 = *reinterpret_cast<const float4*>(feats + (size_t)v * 8);
      float4 a1 = *reinterpret_cast<const float4*>(feats + (size_t)v * 8 + 4);
      __hip_bfloat16 tmp[8] = {
        __float2bfloat16(a0.x), __float2bfloat16(a0.y), __float2bfloat16(a0.z), __float2bfloat16(a0.w),
        __float2bfloat16(a1.x), __float2bfloat16(a1.y), __float2bfloat16(a1.z), __float2bfloat16(a1.w)};
      *reinterpret_cast<bf16x8*>(feats16 + (size_t)v * 8) = *reinterpret_cast<const bf16x8*>(tmp);
    }
    return;
  }
  b -= nbF;
  if (b < 6 * nbW) {  // 384x384 weight transposes (coalesced reads)
    int m = b / nbW;
    int v = (b - m * nbW) * 256 + t;
    if (v >= CDIM * 48) return;
    const float* src;
    __hip_bfloat16* dst;
    switch (m) {
      case 0: src = W_pool; dst = Wt_pe; break;
      case 1: src = W_emb;  dst = Wt_pe + (size_t)CDIM * CDIM; break;
      case 2: src = Wk;     dst = Wt_kv; break;
      case 3: src = Wv;     dst = Wt_kv + (size_t)CDIM * CDIM; break;
      case 4: src = Wq;     dst = Wt_q; break;
      default: src = Wo;    dst = Wt_o; break;
    }
    int k8i = v / CDIM;
    int n = v - k8i * CDIM;        // fast -> coalesced
    int k8 = k8i * 8;
    __hip_bfloat16 tmp[8];
    #pragma unroll
    for (int u = 0; u < 8; ++u) tmp[u] = __float2bfloat16(src[(size_t)(k8 + u) * CDIM + n]);
    *reinterpret_cast<bf16x8*>(dst + (size_t)n * CDIM + k8) = *reinterpret_cast<const bf16x8*>(tmp);
    return;
  }
  b -= 6 * nbW;
  if (b < nbC) {  // Wc [10368][32] -> Wct [32][10368]
    int v = b * 256 + t;
    if (v >= OUTD * (CONVK / 8)) return;
    int k8i = v >> 5;
    int n = v & 31;
    int k8 = k8i * 8;
    __hip_bfloat16 tmp[8];
    #pragma unroll
    for (int u = 0; u < 8; ++u) tmp[u] = __float2bfloat16(Wc[(size_t)(k8 + u) * OUTD + n]);
    *reinterpret_cast<bf16x8*>(Wct + (size_t)n * CONVK + k8) = *reinterpret_cast<const bf16x8*>(tmp);
    return;
  }
  b -= nbC;
  if (b < nbZA) {  // zero encA (enc(-inf) floor), 16B/thread
    size_t v = (size_t)b * 256 + t;
    if (v < (size_t)Mp * 96) {
      uint4 z = {0u, 0u, 0u, 0u};
      reinterpret_cast<uint4*>(encA)[v] = z;
    }
    return;
  }
  b -= nbZA;
  if (b < nbZB) {  // zero encB
    size_t v = (size_t)b * 256 + t;
    if (v < (size_t)Me * 96) {
      uint4 z = {0u, 0u, 0u, 0u};
      reinterpret_cast<uint4*>(encB)[v] = z;
    }
    return;
  }
  b -= nbZB;
  if (b < nbVt) {  // vt init: 0 everywhere, 1.0 on d=48 row of each head
    int v = b * 256 + t;
    int g = Mepad >> 3;
    if (v < 512 * g) {
      int row = v / g;
      int c8 = (v - row * g) * 8;
      __hip_bfloat16 bv = __float2bfloat16(((row & 63) == HD) ? 1.0f : 0.0f);
      __hip_bfloat16 tmp[8] = {bv, bv, bv, bv, bv, bv, bv, bv};
      *reinterpret_cast<bf16x8*>(vt + (size_t)row * Mepad + c8) =
          *reinterpret_cast<const bf16x8*>(tmp);
    }
    return;
  }
  b -= nbVt;
  if (b < nbM) {  // per-batch coord min/max
    if (t < MAXB * 3) { lmin[t] = 0x7fffffff; lmax[t] = (int)0x80000000; }
    __syncthreads();
    int i = b * 256 + t;
    int tot = Me + Mp;
    if (i < tot) {
      const int* r = (i < Me) ? (ec + 4 * i) : (pc + 4 * (i - Me));
      int bb = r[0];
      #pragma unroll
      for (int d = 0; d < 3; ++d) {
        atomicMin(&lmin[bb * 3 + d], r[1 + d]);
        atomicMax(&lmax[bb * 3 + d], r[1 + d]);
      }
    }
    __syncthreads();
    if (t < MAXB * 3) {
      if (lmin[t] != 0x7fffffff) atomicMin(&smin[t], lmin[t]);
      if (lmax[t] != (int)0x80000000) atomicMax(&smax[t], lmax[t]);
    }
    return;
  }
  b -= nbM;
  {  // ebound
    int e = b * 256 + t;
    if (e == 0) { ebv[0] = 0; ebv[bsz[0]] = Me; }
    if (e > 0 && e < Me) {
      int b0 = ec[4 * (e - 1)], b1 = ec[4 * e];
      for (int bb = b0 + 1; bb <= b1; ++bb) ebv[bb] = e;
    }
  }
}

// decode segment-max, add sine PE (fast hw sin/cos), emit bf16 activations
__global__ void pe_kernel(const unsigned* __restrict__ encP, const unsigned* __restrict__ encE,
                          __hip_bfloat16* __restrict__ pool16, __hip_bfloat16* __restrict__ emb16,
                          const int* __restrict__ pc, int Mp,
                          const int* __restrict__ ec, int Me,
                          const int* __restrict__ smin, const int* __restrict__ smax) {
  int gid = blockIdx.x * blockDim.x + threadIdx.x;
  int total = (Mp + Me) * CDIM;
  if (gid >= total) return;
  int row = gid / CDIM, c = gid - row * CDIM;
  const int* coords;
  const unsigned* src;
  __hip_bfloat16* dst;
  int lrow;
  if (row < Me) { lrow = row; coords = ec + 4 * row; src = encE; dst = emb16; }
  else { lrow = row - Me; coords = pc + 4 * lrow; src = encP; dst = pool16; }
  int b = coords[0];
  int dim = c >> 7;
  int i = c & 127;
  int j = i >> 1;
  float x = (float)coords[1 + dim];
  float mn = (float)smin[b * 3 + dim];
  float mx = (float)smax[b * 3 + dim];
  float nrm = (x - mn) / (mx - mn + 1e-6f);
  float freq = exp2f(-(float)j * 0.20762050593046014f);  // 10000^(-j/64)
  float arg = nrm * 6.283185307179586f * freq;
  float pe = (i & 1) ? __cosf(arg) : __sinf(arg);
  float val = dec_f(src[(size_t)lrow * CDIM + c]) + pe;
  dst[(size_t)lrow * CDIM + c] = __float2bfloat16(val);
}

// Unified bf16 MFMA GEMM body (round-10 geometry: BM=128 x BN=64, measured best).
template <int EPI>
__device__ __forceinline__ void mgemm_body(
    int bx, int by,
    __hip_bfloat16 (*As)[72], __hip_bfloat16 (*Bs)[72],
    const __hip_bfloat16* __restrict__ A, int M,
    const __hip_bfloat16* __restrict__ Wt,
    const float* __restrict__ bias0, const float* __restrict__ bias1,
    void* __restrict__ d0, void* __restrict__ d1,
    const int* __restrict__ inv0, const int* __restrict__ inv1,
    int Mepad) {
  const int m0 = bx * 128;
  const int n0 = by * 64;
  const int t = threadIdx.x;
  const int lane = t & 63, w = t >> 6;
  const int wr = w >> 1, wc = w & 1;
  const int lq = lane & 15, lg = lane >> 4;

  f32x4 acc[4][2];
  #pragma unroll
  for (int i = 0; i < 4; ++i) {
    acc[i][0] = (f32x4){0.f, 0.f, 0.f, 0.f};
    acc[i][1] = (f32x4){0.f, 0.f, 0.f, 0.f};
  }
  const int arow = t >> 3;
  const int acol = (t & 7) * 8;

  for (int k0 = 0; k0 < CDIM; k0 += 64) {
    #pragma unroll
    for (int i = 0; i < 4; ++i) {
      int r = arow + i * 32;
      int gr = m0 + r;
      bf16x8 val = zero8();
      if (gr < M) val = *reinterpret_cast<const bf16x8*>(A + (size_t)gr * CDIM + k0 + acol);
      *reinterpret_cast<bf16x8*>(&As[r][acol]) = val;
    }
    #pragma unroll
    for (int i = 0; i < 2; ++i) {
      int r = arow + i * 32;
      bf16x8 val = *reinterpret_cast<const bf16x8*>(Wt + (size_t)(n0 + r) * CDIM + k0 + acol);
      *reinterpret_cast<bf16x8*>(&Bs[r][acol]) = val;
    }
    __syncthreads();
    #pragma unroll
    for (int ks = 0; ks < 2; ++ks) {
      bf16x8 af[4], bfv[2];
      #pragma unroll
      for (int fm = 0; fm < 4; ++fm)
        af[fm] = *reinterpret_cast<const bf16x8*>(&As[wr * 64 + fm * 16 + lq][ks * 32 + lg * 8]);
      #pragma unroll
      for (int fn = 0; fn < 2; ++fn)
        bfv[fn] = *reinterpret_cast<const bf16x8*>(&Bs[wc * 32 + fn * 16 + lq][ks * 32 + lg * 8]);
      #pragma unroll
      for (int fm = 0; fm < 4; ++fm)
        #pragma unroll
        for (int fn = 0; fn < 2; ++fn)
          acc[fm][fn] = mfma16(af[fm], bfv[fn], acc[fm][fn]);
    }
    __syncthreads();
  }

  const bool sec = (n0 >= CDIM);
  const int nb = n0 - (sec ? CDIM : 0) + wc * 32;
  const int nA = nb + lq, nB = nb + 16 + lq;

  if (EPI == 0) {
    const float* bias = sec ? bias1 : bias0;
    unsigned* dst = (unsigned*)(sec ? d1 : d0);
    const int* inv = sec ? inv1 : inv0;
    float bA = bias[nA], bB = bias[nB];
    #pragma unroll
    for (int fm = 0; fm < 4; ++fm) {
      int rbase = m0 + wr * 64 + fm * 16 + lg * 4;
      int cs = -1;
      float mA = 0.f, mB = 0.f;
      #pragma unroll
      for (int j = 0; j < 4; ++j) {
        int r = rbase + j;
        if (r < M) {
          int s = inv[r];
          float vA = acc[fm][0][j] + bA;
          float vB = acc[fm][1][j] + bB;
          if (s == cs) { mA = fmaxf(mA, vA); mB = fmaxf(mB, vB); }
          else {
            if (cs >= 0) {
              atomicMax(&dst[(size_t)cs * CDIM + nA], enc_f(mA));
              atomicMax(&dst[(size_t)cs * CDIM + nB], enc_f(mB));
            }
            cs = s; mA = vA; mB = vB;
          }
        }
      }
      if (cs >= 0) {
        atomicMax(&dst[(size_t)cs * CDIM + nA], enc_f(mA));
        atomicMax(&dst[(size_t)cs * CDIM + nB], enc_f(mB));
      }
    }
  } else if (EPI == 1) {
    float bA = bias0[nA], bB = bias0[nB];
    float* dst = (float*)d0;
    #pragma unroll
    for (int fm = 0; fm < 4; ++fm)
      #pragma unroll
      for (int j = 0; j < 4; ++j) {
        int r = m0 + wr * 64 + fm * 16 + lg * 4 + j;
        if (r < M) {
          dst[(size_t)r * CDIM + nA] = acc[fm][0][j] + bA;
          dst[(size_t)r * CDIM + nB] = acc[fm][1][j] + bB;
        }
      }
  } else if (EPI == 2) {
    // scale = log2(e)/sqrt(48): softmax via exp2 (exact rewrite)
    const float scale = 0.2082350914f;
    float bA = bias0[nA], bB = bias0[nB];
    int hA = nA / HD, dA = nA - hA * HD;
    int hB = nB / HD, dB = nB - hB * HD;
    __hip_bfloat16* dst = (__hip_bfloat16*)d0;
    #pragma unroll
    for (int fm = 0; fm < 4; ++fm)
      #pragma unroll
      for (int j = 0; j < 4; ++j) {
        int r = m0 + wr * 64 + fm * 16 + lg * 4 + j;
        if (r < M) {
          dst[(size_t)r * 512 + hA * 64 + dA] = __float2bfloat16((acc[fm][0][j] + bA) * scale);
          dst[(size_t)r * 512 + hB * 64 + dB] = __float2bfloat16((acc[fm][1][j] + bB) * scale);
        }
      }
  } else {  // EPI 3: K -> k16 [M][512]; V -> vt transposed [h*64+d][Mepad]
    if (!sec) {
      float bA = bias0[nA], bB = bias0[nB];
      int hA = nA / HD, dA = nA - hA * HD;
      int hB = nB / HD, dB = nB - hB * HD;
      __hip_bfloat16* dst = (__hip_bfloat16*)d0;
      #pragma unroll
      for (int fm = 0; fm < 4; ++fm)
        #pragma unroll
        for (int j = 0; j < 4; ++j) {
          int r = m0 + wr * 64 + fm * 16 + lg * 4 + j;
          if (r < M) {
            dst[(size_t)r * 512 + hA * 64 + dA] = __float2bfloat16(acc[fm][0][j] + bA);
            dst[(size_t)r * 512 + hB * 64 + dB] = __float2bfloat16(acc[fm][1][j] + bB);
          }
        }
    } else {
      float bA = bias1[nA], bB = bias1[nB];
      int hA = nA / HD, dA = nA - hA * HD;
      int hB = nB / HD, dB = nB - hB * HD;
      __hip_bfloat16* dst = (__hip_bfloat16*)d1;
      #pragma unroll
      for (int fm = 0; fm < 4; ++fm)
        #pragma unroll
        for (int j = 0; j < 4; ++j) {
          int r = m0 + wr * 64 + fm * 16 + lg * 4 + j;
          if (r < M) {
            dst[(size_t)(hA * 64 + dA) * Mepad + r] = __float2bfloat16(acc[fm][0][j] + bA);
            dst[(size_t)(hB * 64 + dB) * Mepad + r] = __float2bfloat16(acc[fm][1][j] + bB);
          }
        }
    }
  }
  // pad-zero for q16/k16 head lanes d=48..63 (disjoint from data lanes).
  if ((EPI == 2 || EPI == 3) && n0 == 0) {
    __hip_bfloat16* dst = (__hip_bfloat16*)d0;
    for (int c = t; c < 1024; c += 256) {
      int r = m0 + (c >> 3);
      int hx = c & 7;
      if (r < M) {
        bf16x8 z = zero8();
        *reinterpret_cast<bf16x8*>(dst + (size_t)r * 512 + hx * 64 + 48) = z;
        *reinterpret_cast<bf16x8*>(dst + (size_t)r * 512 + hx * 64 + 56) = z;
      }
    }
  }
}

__global__ __launch_bounds__(256) void mgemm0_kernel(
    const __hip_bfloat16* __restrict__ A, int M, const __hip_bfloat16* __restrict__ Wt,
    const float* __restrict__ bias0, const float* __restrict__ bias1,
    unsigned* __restrict__ d0, unsigned* __restrict__ d1,
    const int* __restrict__ inv0, const int* __restrict__ inv1) {
  __shared__ __align__(16) __hip_bfloat16 As[128][72];
  __shared__ __align__(16) __hip_bfloat16 Bs[64][72];
  mgemm_body<0>(blockIdx.x, blockIdx.y, As, Bs, A, M, Wt, bias0, bias1, d0, d1, inv0, inv1, 0);
}

__global__ __launch_bounds__(256) void mgemm1_kernel(
    const __hip_bfloat16* __restrict__ A, int M, const __hip_bfloat16* __restrict__ Wt,
    const float* __restrict__ bias0, float* __restrict__ d0) {
  __shared__ __align__(16) __hip_bfloat16 As[128][72];
  __shared__ __align__(16) __hip_bfloat16 Bs[64][72];
  mgemm_body<1>(blockIdx.x, blockIdx.y, As, Bs, A, M, Wt, bias0, nullptr, d0, nullptr, nullptr, nullptr, 0);
}

// horizontally fused q-projection (EPI2) + kv-projection (EPI3)
__global__ __launch_bounds__(256) void qkv_kernel(
    const __hip_bfloat16* __restrict__ pool16, int Mp, const __hip_bfloat16* __restrict__ Wt_q,
    const float* __restrict__ bq,
    const __hip_bfloat16* __restrict__ emb16, int Me, const __hip_bfloat16* __restrict__ Wt_kv,
    const float* __restrict__ bk, const float* __restrict__ bv,
    __hip_bfloat16* __restrict__ q16, __hip_bfloat16* __restrict__ k16,
    __hip_bfloat16* __restrict__ vt, int Mepad, int nbQ, int gxQ, int gxK) {
  __shared__ __align__(16) __hip_bfloat16 As[128][72];
  __shared__ __align__(16) __hip_bfloat16 Bs[64][72];
  int b = blockIdx.x;
  if (b < nbQ) {
    mgemm_body<2>(b % gxQ, b / gxQ, As, Bs, pool16, Mp, Wt_q, bq, nullptr,
                  q16, nullptr, nullptr, nullptr, 0);
  } else {
    b -= nbQ;
    mgemm_body<3>(b % gxK, b / gxK, As, Bs, emb16, Me, Wt_kv, bk, bv,
                  k16, vt, nullptr, nullptr, Mepad);
  }
}

// MFMA flash attention, round 14: round-10 structure (dbuf LDS, 4 waves,
// one barrier/iter) + flash-decoding e-split: blockIdx.z in {0,1} handles
// half the e-tiles, writing UNNORMALIZED partials (sum p*v per d; sum p via
// ones-column at d=48) to po[z][q][h][64] fp32. Halves combine by addition
// (exact, deterministic). combine_kernel normalizes.
__global__ __launch_bounds__(256) void attn_mfma_kernel(
    const __hip_bfloat16* __restrict__ qb, const __hip_bfloat16* __restrict__ kb,
    const __hip_bfloat16* __restrict__ vt, int Mepad,
    const int* __restrict__ pc, const int* __restrict__ eb,
    int Mp, int Me, float* __restrict__ po) {
  __shared__ __align__(16) __hip_bfloat16 Ks[2][64][72];
  __shared__ __align__(16) __hip_bfloat16 Vs[2][64][72];
  __shared__ __align__(16) __hip_bfloat16 pl[4][16][72];
  __shared__ int sred[4][4];
  const int h = blockIdx.y;
  const int zz = blockIdx.z;
  const int t = threadIdx.x;
  const int wv = t >> 6, lane = t & 63;
  const int lq = lane & 15, lg = lane >> 4;
  const int q0 = blockIdx.x * 64 + wv * 16;

  int lo[4], hi[4];
  #pragma unroll
  for (int r = 0; r < 4; ++r) {
    int q = q0 + lg * 4 + r;
    if (q < Mp) { int b = pc[4 * q]; lo[r] = eb[b]; hi[r] = eb[b + 1]; }
    else { lo[r] = 0x7fffffff; hi[r] = 0; }
  }
  int lomin = min(min(lo[0], lo[1]), min(lo[2], lo[3]));
  int lomax = max(max(lo[0], lo[1]), max(lo[2], lo[3]));
  int himin = min(min(hi[0], hi[1]), min(hi[2], hi[3]));
  int himax = max(max(hi[0], hi[1]), max(hi[2], hi[3]));
  #pragma unroll
  for (int off = 1; off < 64; off <<= 1) {
    lomin = min(lomin, __shfl_xor(lomin, off));
    lomax = max(lomax, __shfl_xor(lomax, off));
    himin = min(himin, __shfl_xor(himin, off));
    himax = max(himax, __shfl_xor(himax, off));
  }
  if (lane == 0) {
    sred[wv][0] = lomin; sred[wv][1] = lomax;
    sred[wv][2] = himin; sred[wv][3] = himax;
  }
  __syncthreads();
  lomin = min(min(sred[0][0], sred[1][0]), min(sred[2][0], sred[3][0]));
  lomax = max(max(sred[0][1], sred[1][1]), max(sred[2][1], sred[3][1]));
  himin = min(min(sred[0][2], sred[1][2]), min(sred[2][2], sred[3][2]));
  himax = max(max(sred[0][3], sred[1][3]), max(sred[2][3], sred[3][3]));

  // split the tile range between the two z-blocks
  const int e0all = lomin & ~63;
  const int nt = (himax > e0all) ? ((himax - e0all + 63) >> 6) : 0;
  const int half = (nt + 1) >> 1;
  const int s0 = e0all + zz * half * 64;
  const int send = min(himax, e0all + (zz ? nt : half) * 64);

  int qrow = min(q0 + lq, Mp - 1);
  const __hip_bfloat16* qp = qb + (size_t)qrow * 512 + h * 64 + lg * 8;
  bf16x8 aq0 = *reinterpret_cast<const bf16x8*>(qp);
  bf16x8 aq1 = *reinterpret_cast<const bf16x8*>(qp + 32);

  const int str = t >> 2;
  const int stc = (t & 3) * 16;
  const __hip_bfloat16* vrow = vt + (size_t)(h * 64 + str) * Mepad + stc;

  f32x4 zero = {0.f, 0.f, 0.f, 0.f};
  f32x4 oacc[4];
  oacc[0] = zero; oacc[1] = zero; oacc[2] = zero; oacc[3] = zero;

  bf16x8 k0, k1, v0, v1;
  auto load_tile = [&](int e0) {
    int er = e0 + str;
    k0 = zero8(); k1 = zero8();
    if (er < Me) {
      const __hip_bfloat16* kp = kb + (size_t)er * 512 + h * 64 + stc;
      k0 = *reinterpret_cast<const bf16x8*>(kp);
      k1 = *reinterpret_cast<const bf16x8*>(kp + 8);
    }
    v0 = *reinterpret_cast<const bf16x8*>(vrow + e0);
    v1 = *reinterpret_cast<const bf16x8*>(vrow + e0 + 8);
  };
  auto store_tile = [&](int nb) {
    *reinterpret_cast<bf16x8*>(&Ks[nb][str][stc]) = k0;
    *reinterpret_cast<bf16x8*>(&Ks[nb][str][stc + 8]) = k1;
    *reinterpret_cast<bf16x8*>(&Vs[nb][str][stc]) = v0;
    *reinterpret_cast<bf16x8*>(&Vs[nb][str][stc + 8]) = v1;
  };
  if (s0 < send) {
    load_tile(s0);
    store_tile(0);
    if (s0 + 64 < send) load_tile(s0 + 64);
  }

  int it = 0;
  for (int e0 = s0; e0 < send; e0 += 64, ++it) {
    __syncthreads();
    const int cur = it & 1;
    if (e0 + 64 < send) {
      store_tile(cur ^ 1);
      if (e0 + 128 < send) load_tile(e0 + 128);
    }

    f32x4 sf[4];
    #pragma unroll
    for (int s = 0; s < 4; ++s) {
      bf16x8 bk0 = *reinterpret_cast<const bf16x8*>(&Ks[cur][s * 16 + lq][lg * 8]);
      bf16x8 bk1 = *reinterpret_cast<const bf16x8*>(&Ks[cur][s * 16 + lq][32 + lg * 8]);
      f32x4 z = zero;
      z = mfma16(aq0, bk0, z);
      z = mfma16(aq1, bk1, z);
      sf[s] = z;
    }
    const bool interior = (e0 >= lomax) && (e0 + 64 <= himin);
    if (interior) {
      #pragma unroll
      for (int s = 0; s < 4; ++s)
        #pragma unroll
        for (int r = 0; r < 4; ++r)
          pl[wv][lg * 4 + r][s * 16 + lq] = __float2bfloat16(exp2f(sf[s][r]));
    } else {
      #pragma unroll
      for (int s = 0; s < 4; ++s) {
        int e = e0 + s * 16 + lq;
        #pragma unroll
        for (int r = 0; r < 4; ++r) {
          bool m = (e >= lo[r]) && (e < hi[r]);
          float p = m ? exp2f(sf[s][r]) : 0.f;
          pl[wv][lg * 4 + r][s * 16 + lq] = __float2bfloat16(p);
        }
      }
    }
    asm volatile("s_waitcnt lgkmcnt(0)" ::: "memory");
    __builtin_amdgcn_sched_barrier(0);  // rule #18
    #pragma unroll
    for (int ks = 0; ks < 2; ++ks) {
      bf16x8 ap = *reinterpret_cast<const bf16x8*>(&pl[wv][lq][ks * 32 + lg * 8]);
      #pragma unroll
      for (int dt = 0; dt < 4; ++dt) {
        bf16x8 bv = *reinterpret_cast<const bf16x8*>(&Vs[cur][dt * 16 + lq][ks * 32 + lg * 8]);
        oacc[dt] = mfma16(ap, bv, oacc[dt]);
      }
    }
  }

  // write unnormalized partials (always — combine needs defined values)
  #pragma unroll
  for (int r = 0; r < 4; ++r) {
    int q = q0 + lg * 4 + r;
    if (q < Mp) {
      float* pp = po + (((size_t)zz * Mp + q) * NHEAD + h) * 64;
      #pragma unroll
      for (int dt = 0; dt < 4; ++dt) pp[dt * 16 + lq] = oacc[dt][r];
    }
  }
}

// combine the two e-half partials: ob16[q][h*48+d] = (o0+o1) / (l0+l1)
__global__ void combine_kernel(const float* __restrict__ po, int Mp,
                               __hip_bfloat16* __restrict__ ob) {
  int gid = blockIdx.x * 256 + threadIdx.x;
  if (gid >= Mp * CDIM) return;
  int q = gid / CDIM, c = gid - q * CDIM;
  int h = c / HD, d = c - h * HD;
  const float* p0 = po + (((size_t)q) * NHEAD + h) * 64;
  const float* p1 = po + (((size_t)(Mp + q)) * NHEAD + h) * 64;
  float l = p0[HD] + p1[HD];
  float v = p0[d] + p1[d];
  ob[(size_t)q * CDIM + c] = __float2bfloat16(l > 0.f ? v / l : 0.f);
}

__global__ void newf16_kernel(const float* __restrict__ feats, const float* __restrict__ o2,
                              const int* __restrict__ pinv, __hip_bfloat16* __restrict__ nf,
                              int N) {
  int v = blockIdx.x * 256 + threadIdx.x;
  if (v >= N * 48) return;
  int n = v / 48, c8 = (v - n * 48) * 8;
  const float* fp = feats + (size_t)n * CDIM + c8;
  const float* op = o2 + (size_t)pinv[n] * CDIM + c8;
  float4 a0 = *reinterpret_cast<const float4*>(fp);
  float4 a1 = *reinterpret_cast<const float4*>(fp + 4);
  float4 b0 = *reinterpret_cast<const float4*>(op);
  float4 b1 = *reinterpret_cast<const float4*>(op + 4);
  __hip_bfloat16 tmp[8] = {
    __float2bfloat16(a0.x + b0.x), __float2bfloat16(a0.y + b0.y),
    __float2bfloat16(a0.z + b0.z), __float2bfloat16(a0.w + b0.w),
    __float2bfloat16(a1.x + b1.x), __float2bfloat16(a1.y + b1.y),
    __float2bfloat16(a1.z + b1.z), __float2bfloat16(a1.w + b1.w)};
  *reinterpret_cast<bf16x8*>(nf + (size_t)v * 8) = *reinterpret_cast<const bf16x8*>(tmp);
}

// conv as MFMA GEMM: M=N rows, 32 cols, K split by tap groups (9 x 3 taps).
__global__ __launch_bounds__(256) void mconv_kernel(
    const __hip_bfloat16* __restrict__ nf, const int* __restrict__ nbr,
    const __hip_bfloat16* __restrict__ Wct, float* __restrict__ outp, int N) {
  __shared__ __align__(16) __hip_bfloat16 As[128][72];
  __shared__ __align__(16) __hip_bfloat16 Bs[32][72];
  __shared__ int jrow[128];
  const int n0 = blockIdx.x * 128;
  const int kg = blockIdx.y;
  const int t = threadIdx.x;
  const int lane = t & 63, w = t >> 6;
  const int lq = lane & 15, lg = lane >> 4;
  f32x4 acc[2][2];
  acc[0][0] = (f32x4){0.f,0.f,0.f,0.f}; acc[0][1] = acc[0][0];
  acc[1][0] = acc[0][0]; acc[1][1] = acc[0][0];
  const int arow = t >> 3, acol = (t & 7) * 8;

  for (int kk = kg * 3; kk < kg * 3 + 3; ++kk) {
    __syncthreads();
    if (t < 128) {
      int n = n0 + t;
      jrow[t] = (n < N) ? nbr[(size_t)n * 27 + kk] : -1;
    }
    __syncthreads();
    for (int c0 = 0; c0 < CDIM; c0 += 64) {
      #pragma unroll
      for (int i = 0; i < 4; ++i) {
        int r = arow + i * 32;
        int j = jrow[r];
        bf16x8 val = zero8();
        if (j >= 0) val = *reinterpret_cast<const bf16x8*>(nf + (size_t)j * CDIM + c0 + acol);
        *reinterpret_cast<bf16x8*>(&As[r][acol]) = val;
      }
      {
        int r = t >> 3;
        bf16x8 val = *reinterpret_cast<const bf16x8*>(Wct + (size_t)r * CONVK + kk * CDIM + c0 + acol);
        *reinterpret_cast<bf16x8*>(&Bs[r][acol]) = val;
      }
      __syncthreads();
      #pragma unroll
      for (int ks = 0; ks < 2; ++ks) {
        bf16x8 af[2], bfv[2];
        #pragma unroll
        for (int fm = 0; fm < 2; ++fm)
          af[fm] = *reinterpret_cast<const bf16x8*>(&As[w * 32 + fm * 16 + lq][ks * 32 + lg * 8]);
        #pragma unroll
        for (int fn = 0; fn < 2; ++fn)
          bfv[fn] = *reinterpret_cast<const bf16x8*>(&Bs[fn * 16 + lq][ks * 32 + lg * 8]);
        #pragma unroll
        for (int fm = 0; fm < 2; ++fm)
          #pragma unroll
          for (int fn = 0; fn < 2; ++fn)
            acc[fm][fn] = mfma16(af[fm], bfv[fn], acc[fm][fn]);
      }
      __syncthreads();
    }
  }
  #pragma unroll
  for (int fm = 0; fm < 2; ++fm)
    #pragma unroll
    for (int j = 0; j < 4; ++j) {
      int r = n0 + w * 32 + fm * 16 + lg * 4 + j;
      if (r < N) {
        #pragma unroll
        for (int fn = 0; fn < 2; ++fn)
          outp[((size_t)kg * N + r) * OUTD + fn * 16 + lq] = acc[fm][fn][j];
      }
    }
}

__global__ void conv_reduce_kernel(const float* __restrict__ outp,
                                   const float* __restrict__ bc,
                                   float* __restrict__ out, int N) {
  int v = blockIdx.x * 256 + threadIdx.x;
  if (v >= N * OUTD) return;
  int oo = v & (OUTD - 1);
  float s = bc[oo];
  #pragma unroll
  for (int kg = 0; kg < 9; ++kg) s += outp[(size_t)kg * N * OUTD + v];
  out[v] = s;
}

extern "C" void kernel_launch(void* const* d_in, const int* in_sizes, int n_in,
                              void* d_out, int out_size, void* d_ws, size_t ws_size,
                              hipStream_t stream) {
  const float* feats  = (const float*)d_in[0];
  const float* W_pool = (const float*)d_in[1];
  const float* b_pool = (const float*)d_in[2];
  const float* W_emb  = (const float*)d_in[3];
  const float* b_emb  = (const float*)d_in[4];
  const float* Wq = (const float*)d_in[5];  const float* bq = (const float*)d_in[6];
  const float* Wk = (const float*)d_in[7];  const float* bk = (const float*)d_in[8];
  const float* Wv = (const float*)d_in[9];  const float* bv = (const float*)d_in[10];
  const float* Wo = (const float*)d_in[11]; const float* bo = (const float*)d_in[12];
  const float* Wc = (const float*)d_in[13]; const float* bc = (const float*)d_in[14];
  const int* pool_inv    = (const int*)d_in[15];
  const int* pool_coords = (const int*)d_in[16];
  const int* emb_inv     = (const int*)d_in[17];
  const int* emb_coords  = (const int*)d_in[18];
  const int* nbr         = (const int*)d_in[19];
  const int* bsz         = (const int*)d_in[20];
  int N  = in_sizes[0] / CDIM;
  int Mp = in_sizes[16] / 4;
  int Me = in_sizes[18] / 4;
  int Mepad = ((Me >> 6) + 2) << 6;

  char* wsb = (char*)d_ws;
  size_t off = 0;
  auto alloc = [&](size_t bytes) { void* p = wsb + off; off += (bytes + 255) & ~(size_t)255; return p; };
  unsigned* encA = (unsigned*)alloc((size_t)Mp * CDIM * 4);
  unsigned* encB = (unsigned*)alloc((size_t)Me * CDIM * 4);
  __hip_bfloat16* vt = (__hip_bfloat16*)alloc((size_t)512 * Mepad * 2);
  __hip_bfloat16* pool16  = (__hip_bfloat16*)alloc((size_t)Mp * CDIM * 2);
  __hip_bfloat16* emb16   = (__hip_bfloat16*)alloc((size_t)Me * CDIM * 2);
  __hip_bfloat16* feats16 = (__hip_bfloat16*)alloc((size_t)N * CDIM * 2);
  float* o2 = (float*)alloc((size_t)Mp * CDIM * 4 > (size_t)9 * N * OUTD * 4
                                ? (size_t)Mp * CDIM * 4 : (size_t)9 * N * OUTD * 4);
  __hip_bfloat16* Wt_pe = (__hip_bfloat16*)alloc((size_t)768 * CDIM * 2);
  __hip_bfloat16* Wt_kv = (__hip_bfloat16*)alloc((size_t)768 * CDIM * 2);
  __hip_bfloat16* Wt_q  = (__hip_bfloat16*)alloc((size_t)CDIM * CDIM * 2);
  __hip_bfloat16* Wt_o  = (__hip_bfloat16*)alloc((size_t)CDIM * CDIM * 2);
  __hip_bfloat16* Wct   = (__hip_bfloat16*)alloc((size_t)OUTD * CONVK * 2);
  float* po = (float*)alloc((size_t)2 * Mp * NHEAD * 64 * 4);   // attn partials
  int* smin = (int*)alloc(MAXB * 3 * 4);
  int* smax = (int*)alloc(MAXB * 3 * 4);
  int* eb   = (int*)alloc((MAXB + 1) * 4);

  __hip_bfloat16* q16  = (__hip_bfloat16*)encA;   // [Mp][512]
  __hip_bfloat16* k16  = (__hip_bfloat16*)encB;   // [Me][512]
  __hip_bfloat16* ob16 = pool16;                  // [Mp][384]
  __hip_bfloat16* newf16 = feats16;               // [N][384]
  float* outp = o2;                               // [9][N][32]

  init_small_kernel<<<1, 64, 0, stream>>>(smin, smax, eb);

  int nbF  = (N * 48 + 255) / 256;
  int nbW  = (CDIM * 48 + 255) / 256;
  int nbC  = (OUTD * (CONVK / 8) + 255) / 256;
  int nbZA = ((Mp * 96) + 255) / 256;
  int nbZB = ((Me * 96) + 255) / 256;
  int nbVt = ((512 * (Mepad >> 3)) + 255) / 256;
  int nbM  = (Mp + Me + 255) / 256;
  int nbE  = (Me + 255) / 256;
  prep_kernel<<<nbF + 6 * nbW + nbC + nbZA + nbZB + nbVt + nbM + nbE, 256, 0, stream>>>(
      feats, feats16, N, W_pool, W_emb, Wk, Wv, Wq, Wo,
      Wt_pe, Wt_kv, Wt_q, Wt_o, Wc, Wct, encA, encB, vt, Mepad,
      emb_coords, pool_coords, Mp, Me, bsz, smin, smax, eb,
      nbF, nbW, nbC, nbZA, nbZB, nbVt, nbM);

  mgemm0_kernel<<<dim3((N + 127) / 128, 12), 256, 0, stream>>>(
      feats16, N, Wt_pe, b_pool, b_emb, encA, encB, pool_inv, emb_inv);
  pe_kernel<<<((Mp + Me) * CDIM + 255) / 256, 256, 0, stream>>>(
      encA, encB, pool16, emb16, pool_coords, Mp, emb_coords, Me, smin, smax);

  // fused q + kv projections (pads zeroed in-kernel)
  {
    int gxQ = (Mp + 127) / 128, gxK = (Me + 127) / 128;
    int nbQ = gxQ * 6;
    qkv_kernel<<<nbQ + gxK * 12, 256, 0, stream>>>(
        pool16, Mp, Wt_q, bq, emb16, Me, Wt_kv, bk, bv,
        q16, k16, vt, Mepad, nbQ, gxQ, gxK);
  }

  attn_mfma_kernel<<<dim3((Mp + 63) / 64, NHEAD, 2), 256, 0, stream>>>(
      q16, k16, vt, Mepad, pool_coords, eb, Mp, Me, po);
  combine_kernel<<<(Mp * CDIM + 255) / 256, 256, 0, stream>>>(po, Mp, ob16);

  mgemm1_kernel<<<dim3((Mp + 127) / 128, 6), 256, 0, stream>>>(
      ob16, Mp, Wt_o, bo, o2);

  newf16_kernel<<<(N * 48 + 255) / 256, 256, 0, stream>>>(feats, o2, pool_inv, newf16, N);

  mconv_kernel<<<dim3((N + 127) / 128, 9), 256, 0, stream>>>(newf16, nbr, Wct, outp, N);
  conv_reduce_kernel<<<(N * OUTD + 255) / 256, 256, 0, stream>>>(outp, bc, (float*)d_out, N);
}

// Round 15
// 159.191 us; speedup vs baseline: 1.2725x; 1.0576x over previous
//
#include <hip/hip_runtime.h>
#include <hip/hip_bf16.h>
#include <math.h>

#define CDIM 384
#define NHEAD 8
#define HD 48
#define OUTD 32
#define MAXB 16
#define CONVK 10368  // 27*384

typedef __bf16 bf16x8 __attribute__((ext_vector_type(8)));
typedef float f32x4 __attribute__((ext_vector_type(4)));

__device__ __forceinline__ f32x4 mfma16(bf16x8 a, bf16x8 b, f32x4 c) {
  return __builtin_amdgcn_mfma_f32_16x16x32_bf16(a, b, c, 0, 0, 0);
}
__device__ __forceinline__ bf16x8 zero8() {
  bf16x8 z = {(__bf16)0.f, (__bf16)0.f, (__bf16)0.f, (__bf16)0.f,
              (__bf16)0.f, (__bf16)0.f, (__bf16)0.f, (__bf16)0.f};
  return z;
}

// ---- order-preserving float<->uint encoding for atomicMax segment max ----
__device__ __forceinline__ unsigned enc_f(float f) {
  unsigned u = __float_as_uint(f);
  return (u & 0x80000000u) ? ~u : (u | 0x80000000u);
}
__device__ __forceinline__ float dec_f(unsigned u) {
  unsigned v = (u & 0x80000000u) ? (u ^ 0x80000000u) : ~u;
  return __uint_as_float(v);
}

// tiny init: smin/smax sentinels + eb zeros
__global__ void init_small_kernel(int* smin, int* smax, int* eb) {
  int t = threadIdx.x;
  if (t < MAXB * 3) { smin[t] = 0x7fffffff; smax[t] = (int)0x80000000; }
  if (t <= MAXB) eb[t] = 0;
}

// fused one-shot prep: feats->bf16, 6x W^T, Wc^T, zero encA/encB, vt init,
// coord minmax, ebound. No hipMemsetAsync anywhere in the graph.
__global__ __launch_bounds__(256) void prep_kernel(
    const float* __restrict__ feats, __hip_bfloat16* __restrict__ feats16, int N,
    const float* __restrict__ W_pool, const float* __restrict__ W_emb,
    const float* __restrict__ Wk, const float* __restrict__ Wv,
    const float* __restrict__ Wq, const float* __restrict__ Wo,
    __hip_bfloat16* __restrict__ Wt_pe, __hip_bfloat16* __restrict__ Wt_kv,
    __hip_bfloat16* __restrict__ Wt_q, __hip_bfloat16* __restrict__ Wt_o,
    const float* __restrict__ Wc, __hip_bfloat16* __restrict__ Wct,
    unsigned* __restrict__ encA, unsigned* __restrict__ encB,
    __hip_bfloat16* __restrict__ vt, int Mepad,
    const int* __restrict__ ec, const int* __restrict__ pc, int Mp, int Me,
    const int* __restrict__ bsz, int* smin, int* smax, int* ebv,
    int nbF, int nbW, int nbC, int nbZA, int nbZB, int nbVt, int nbM) {
  __shared__ int lmin[MAXB * 3], lmax[MAXB * 3];
  int b = blockIdx.x;
  int t = threadIdx.x;
  if (b < nbF) {  // feats -> bf16
    int v = b * 256 + t;
    if (v < N * 48) {
      float4 a0 = *reinterpret_cast<const float4*>(feats + (size_t)v * 8);
      float4 a1 = *reinterpret_cast<const float4*>(feats + (size_t)v * 8 + 4);
      __hip_bfloat16 tmp[8] = {
        __float2bfloat16(a0.x), __float2bfloat16(a0.y), __float2bfloat16(a0.z), __float2bfloat16(a0.w),
        __float2bfloat16(a1.x), __float2bfloat16(a1.y), __float2bfloat16(a1.z), __float2bfloat16(a1.w)};
      *reinterpret_cast<bf16x8*>(feats16 + (size_t)v * 8) = *reinterpret_cast<const bf16x8*>(tmp);
    }
    return;
  }
  b -= nbF;
  if (b < 6 * nbW) {  // 384x384 weight transposes (coalesced reads)
    int m = b / nbW;
    int v = (b - m * nbW) * 256 + t;
    if (v >= CDIM * 48) return;
    const float* src;
    __hip_bfloat16* dst;
    switch (m) {
      case 0: src = W_pool; dst = Wt_pe; break;
      case 1: src = W_emb;  dst = Wt_pe + (size_t)CDIM * CDIM; break;
      case 2: src = Wk;     dst = Wt_kv; break;
      case 3: src = Wv;     dst = Wt_kv + (size_t)CDIM * CDIM; break;
      case 4: src = Wq;     dst = Wt_q; break;
      default: src = Wo;    dst = Wt_o; break;
    }
    int k8i = v / CDIM;
    int n = v - k8i * CDIM;        // fast -> coalesced
    int k8 = k8i * 8;
    __hip_bfloat16 tmp[8];
    #pragma unroll
    for (int u = 0; u < 8; ++u) tmp[u] = __float2bfloat16(src[(size_t)(k8 + u) * CDIM + n]);
    *reinterpret_cast<bf16x8*>(dst + (size_t)n * CDIM + k8) = *reinterpret_cast<const bf16x8*>(tmp);
    return;
  }
  b -= 6 * nbW;
  if (b < nbC) {  // Wc [10368][32] -> Wct [32][10368]
    int v = b * 256 + t;
    if (v >= OUTD * (CONVK / 8)) return;
    int k8i = v >> 5;
    int n = v & 31;
    int k8 = k8i * 8;
    __hip_bfloat16 tmp[8];
    #pragma unroll
    for (int u = 0; u < 8; ++u) tmp[u] = __float2bfloat16(Wc[(size_t)(k8 + u) * OUTD + n]);
    *reinterpret_cast<bf16x8*>(Wct + (size_t)n * CONVK + k8) = *reinterpret_cast<const bf16x8*>(tmp);
    return;
  }
  b -= nbC;
  if (b < nbZA) {  // zero encA (enc(-inf) floor), 16B/thread
    size_t v = (size_t)b * 256 + t;
    if (v < (size_t)Mp * 96) {
      uint4 z = {0u, 0u, 0u, 0u};
      reinterpret_cast<uint4*>(encA)[v] = z;
    }
    return;
  }
  b -= nbZA;
  if (b < nbZB) {  // zero encB
    size_t v = (size_t)b * 256 + t;
    if (v < (size_t)Me * 96) {
      uint4 z = {0u, 0u, 0u, 0u};
      reinterpret_cast<uint4*>(encB)[v] = z;
    }
    return;
  }
  b -= nbZB;
  if (b < nbVt) {  // vt init: 0 everywhere, 1.0 on d=48 row of each head
    int v = b * 256 + t;
    int g = Mepad >> 3;
    if (v < 512 * g) {
      int row = v / g;
      int c8 = (v - row * g) * 8;
      __hip_bfloat16 bv = __float2bfloat16(((row & 63) == HD) ? 1.0f : 0.0f);
      __hip_bfloat16 tmp[8] = {bv, bv, bv, bv, bv, bv, bv, bv};
      *reinterpret_cast<bf16x8*>(vt + (size_t)row * Mepad + c8) =
          *reinterpret_cast<const bf16x8*>(tmp);
    }
    return;
  }
  b -= nbVt;
  if (b < nbM) {  // per-batch coord min/max
    if (t < MAXB * 3) { lmin[t] = 0x7fffffff; lmax[t] = (int)0x80000000; }
    __syncthreads();
    int i = b * 256 + t;
    int tot = Me + Mp;
    if (i < tot) {
      const int* r = (i < Me) ? (ec + 4 * i) : (pc + 4 * (i - Me));
      int bb = r[0];
      #pragma unroll
      for (int d = 0; d < 3; ++d) {
        atomicMin(&lmin[bb * 3 + d], r[1 + d]);
        atomicMax(&lmax[bb * 3 + d], r[1 + d]);
      }
    }
    __syncthreads();
    if (t < MAXB * 3) {
      if (lmin[t] != 0x7fffffff) atomicMin(&smin[t], lmin[t]);
      if (lmax[t] != (int)0x80000000) atomicMax(&smax[t], lmax[t]);
    }
    return;
  }
  b -= nbM;
  {  // ebound
    int e = b * 256 + t;
    if (e == 0) { ebv[0] = 0; ebv[bsz[0]] = Me; }
    if (e > 0 && e < Me) {
      int b0 = ec[4 * (e - 1)], b1 = ec[4 * e];
      for (int bb = b0 + 1; bb <= b1; ++bb) ebv[bb] = e;
    }
  }
}

// decode segment-max, add sine PE (fast hw sin/cos), emit bf16 activations
__global__ void pe_kernel(const unsigned* __restrict__ encP, const unsigned* __restrict__ encE,
                          __hip_bfloat16* __restrict__ pool16, __hip_bfloat16* __restrict__ emb16,
                          const int* __restrict__ pc, int Mp,
                          const int* __restrict__ ec, int Me,
                          const int* __restrict__ smin, const int* __restrict__ smax) {
  int gid = blockIdx.x * blockDim.x + threadIdx.x;
  int total = (Mp + Me) * CDIM;
  if (gid >= total) return;
  int row = gid / CDIM, c = gid - row * CDIM;
  const int* coords;
  const unsigned* src;
  __hip_bfloat16* dst;
  int lrow;
  if (row < Me) { lrow = row; coords = ec + 4 * row; src = encE; dst = emb16; }
  else { lrow = row - Me; coords = pc + 4 * lrow; src = encP; dst = pool16; }
  int b = coords[0];
  int dim = c >> 7;
  int i = c & 127;
  int j = i >> 1;
  float x = (float)coords[1 + dim];
  float mn = (float)smin[b * 3 + dim];
  float mx = (float)smax[b * 3 + dim];
  float nrm = (x - mn) / (mx - mn + 1e-6f);
  float freq = exp2f(-(float)j * 0.20762050593046014f);  // 10000^(-j/64)
  float arg = nrm * 6.283185307179586f * freq;
  float pe = (i & 1) ? __cosf(arg) : __sinf(arg);
  float val = dec_f(src[(size_t)lrow * CDIM + c]) + pe;
  dst[(size_t)lrow * CDIM + c] = __float2bfloat16(val);
}

// Unified bf16 MFMA GEMM body (round-10 geometry: BM=128 x BN=64, measured
// best across rounds 10-14). EPI2/EPI3 n0==0 blocks zero head-pad lanes.
template <int EPI>
__device__ __forceinline__ void mgemm_body(
    int bx, int by,
    __hip_bfloat16 (*As)[72], __hip_bfloat16 (*Bs)[72],
    const __hip_bfloat16* __restrict__ A, int M,
    const __hip_bfloat16* __restrict__ Wt,
    const float* __restrict__ bias0, const float* __restrict__ bias1,
    void* __restrict__ d0, void* __restrict__ d1,
    const int* __restrict__ inv0, const int* __restrict__ inv1,
    int Mepad) {
  const int m0 = bx * 128;
  const int n0 = by * 64;
  const int t = threadIdx.x;
  const int lane = t & 63, w = t >> 6;
  const int wr = w >> 1, wc = w & 1;
  const int lq = lane & 15, lg = lane >> 4;

  f32x4 acc[4][2];
  #pragma unroll
  for (int i = 0; i < 4; ++i) {
    acc[i][0] = (f32x4){0.f, 0.f, 0.f, 0.f};
    acc[i][1] = (f32x4){0.f, 0.f, 0.f, 0.f};
  }
  const int arow = t >> 3;
  const int acol = (t & 7) * 8;

  for (int k0 = 0; k0 < CDIM; k0 += 64) {
    #pragma unroll
    for (int i = 0; i < 4; ++i) {
      int r = arow + i * 32;
      int gr = m0 + r;
      bf16x8 val = zero8();
      if (gr < M) val = *reinterpret_cast<const bf16x8*>(A + (size_t)gr * CDIM + k0 + acol);
      *reinterpret_cast<bf16x8*>(&As[r][acol]) = val;
    }
    #pragma unroll
    for (int i = 0; i < 2; ++i) {
      int r = arow + i * 32;
      bf16x8 val = *reinterpret_cast<const bf16x8*>(Wt + (size_t)(n0 + r) * CDIM + k0 + acol);
      *reinterpret_cast<bf16x8*>(&Bs[r][acol]) = val;
    }
    __syncthreads();
    #pragma unroll
    for (int ks = 0; ks < 2; ++ks) {
      bf16x8 af[4], bfv[2];
      #pragma unroll
      for (int fm = 0; fm < 4; ++fm)
        af[fm] = *reinterpret_cast<const bf16x8*>(&As[wr * 64 + fm * 16 + lq][ks * 32 + lg * 8]);
      #pragma unroll
      for (int fn = 0; fn < 2; ++fn)
        bfv[fn] = *reinterpret_cast<const bf16x8*>(&Bs[wc * 32 + fn * 16 + lq][ks * 32 + lg * 8]);
      #pragma unroll
      for (int fm = 0; fm < 4; ++fm)
        #pragma unroll
        for (int fn = 0; fn < 2; ++fn)
          acc[fm][fn] = mfma16(af[fm], bfv[fn], acc[fm][fn]);
    }
    __syncthreads();
  }

  const bool sec = (n0 >= CDIM);
  const int nb = n0 - (sec ? CDIM : 0) + wc * 32;
  const int nA = nb + lq, nB = nb + 16 + lq;

  if (EPI == 0) {
    const float* bias = sec ? bias1 : bias0;
    unsigned* dst = (unsigned*)(sec ? d1 : d0);
    const int* inv = sec ? inv1 : inv0;
    float bA = bias[nA], bB = bias[nB];
    #pragma unroll
    for (int fm = 0; fm < 4; ++fm) {
      int rbase = m0 + wr * 64 + fm * 16 + lg * 4;
      int cs = -1;
      float mA = 0.f, mB = 0.f;
      #pragma unroll
      for (int j = 0; j < 4; ++j) {
        int r = rbase + j;
        if (r < M) {
          int s = inv[r];
          float vA = acc[fm][0][j] + bA;
          float vB = acc[fm][1][j] + bB;
          if (s == cs) { mA = fmaxf(mA, vA); mB = fmaxf(mB, vB); }
          else {
            if (cs >= 0) {
              atomicMax(&dst[(size_t)cs * CDIM + nA], enc_f(mA));
              atomicMax(&dst[(size_t)cs * CDIM + nB], enc_f(mB));
            }
            cs = s; mA = vA; mB = vB;
          }
        }
      }
      if (cs >= 0) {
        atomicMax(&dst[(size_t)cs * CDIM + nA], enc_f(mA));
        atomicMax(&dst[(size_t)cs * CDIM + nB], enc_f(mB));
      }
    }
  } else if (EPI == 1) {
    float bA = bias0[nA], bB = bias0[nB];
    float* dst = (float*)d0;
    #pragma unroll
    for (int fm = 0; fm < 4; ++fm)
      #pragma unroll
      for (int j = 0; j < 4; ++j) {
        int r = m0 + wr * 64 + fm * 16 + lg * 4 + j;
        if (r < M) {
          dst[(size_t)r * CDIM + nA] = acc[fm][0][j] + bA;
          dst[(size_t)r * CDIM + nB] = acc[fm][1][j] + bB;
        }
      }
  } else if (EPI == 2) {
    // scale = log2(e)/sqrt(48): softmax via exp2 (exact rewrite)
    const float scale = 0.2082350914f;
    float bA = bias0[nA], bB = bias0[nB];
    int hA = nA / HD, dA = nA - hA * HD;
    int hB = nB / HD, dB = nB - hB * HD;
    __hip_bfloat16* dst = (__hip_bfloat16*)d0;
    #pragma unroll
    for (int fm = 0; fm < 4; ++fm)
      #pragma unroll
      for (int j = 0; j < 4; ++j) {
        int r = m0 + wr * 64 + fm * 16 + lg * 4 + j;
        if (r < M) {
          dst[(size_t)r * 512 + hA * 64 + dA] = __float2bfloat16((acc[fm][0][j] + bA) * scale);
          dst[(size_t)r * 512 + hB * 64 + dB] = __float2bfloat16((acc[fm][1][j] + bB) * scale);
        }
      }
  } else {  // EPI 3: K -> k16 [M][512]; V -> vt transposed [h*64+d][Mepad]
    if (!sec) {
      float bA = bias0[nA], bB = bias0[nB];
      int hA = nA / HD, dA = nA - hA * HD;
      int hB = nB / HD, dB = nB - hB * HD;
      __hip_bfloat16* dst = (__hip_bfloat16*)d0;
      #pragma unroll
      for (int fm = 0; fm < 4; ++fm)
        #pragma unroll
        for (int j = 0; j < 4; ++j) {
          int r = m0 + wr * 64 + fm * 16 + lg * 4 + j;
          if (r < M) {
            dst[(size_t)r * 512 + hA * 64 + dA] = __float2bfloat16(acc[fm][0][j] + bA);
            dst[(size_t)r * 512 + hB * 64 + dB] = __float2bfloat16(acc[fm][1][j] + bB);
          }
        }
    } else {
      float bA = bias1[nA], bB = bias1[nB];
      int hA = nA / HD, dA = nA - hA * HD;
      int hB = nB / HD, dB = nB - hB * HD;
      __hip_bfloat16* dst = (__hip_bfloat16*)d1;
      #pragma unroll
      for (int fm = 0; fm < 4; ++fm)
        #pragma unroll
        for (int j = 0; j < 4; ++j) {
          int r = m0 + wr * 64 + fm * 16 + lg * 4 + j;
          if (r < M) {
            dst[(size_t)(hA * 64 + dA) * Mepad + r] = __float2bfloat16(acc[fm][0][j] + bA);
            dst[(size_t)(hB * 64 + dB) * Mepad + r] = __float2bfloat16(acc[fm][1][j] + bB);
          }
        }
    }
  }
  // pad-zero for q16/k16 head lanes d=48..63 (disjoint from data lanes).
  if ((EPI == 2 || EPI == 3) && n0 == 0) {
    __hip_bfloat16* dst = (__hip_bfloat16*)d0;
    for (int c = t; c < 1024; c += 256) {
      int r = m0 + (c >> 3);
      int hx = c & 7;
      if (r < M) {
        bf16x8 z = zero8();
        *reinterpret_cast<bf16x8*>(dst + (size_t)r * 512 + hx * 64 + 48) = z;
        *reinterpret_cast<bf16x8*>(dst + (size_t)r * 512 + hx * 64 + 56) = z;
      }
    }
  }
}

__global__ __launch_bounds__(256) void mgemm0_kernel(
    const __hip_bfloat16* __restrict__ A, int M, const __hip_bfloat16* __restrict__ Wt,
    const float* __restrict__ bias0, const float* __restrict__ bias1,
    unsigned* __restrict__ d0, unsigned* __restrict__ d1,
    const int* __restrict__ inv0, const int* __restrict__ inv1) {
  __shared__ __align__(16) __hip_bfloat16 As[128][72];
  __shared__ __align__(16) __hip_bfloat16 Bs[64][72];
  mgemm_body<0>(blockIdx.x, blockIdx.y, As, Bs, A, M, Wt, bias0, bias1, d0, d1, inv0, inv1, 0);
}

__global__ __launch_bounds__(256) void mgemm1_kernel(
    const __hip_bfloat16* __restrict__ A, int M, const __hip_bfloat16* __restrict__ Wt,
    const float* __restrict__ bias0, float* __restrict__ d0) {
  __shared__ __align__(16) __hip_bfloat16 As[128][72];
  __shared__ __align__(16) __hip_bfloat16 Bs[64][72];
  mgemm_body<1>(blockIdx.x, blockIdx.y, As, Bs, A, M, Wt, bias0, nullptr, d0, nullptr, nullptr, nullptr, 0);
}

// horizontally fused q-projection (EPI2) + kv-projection (EPI3)
__global__ __launch_bounds__(256) void qkv_kernel(
    const __hip_bfloat16* __restrict__ pool16, int Mp, const __hip_bfloat16* __restrict__ Wt_q,
    const float* __restrict__ bq,
    const __hip_bfloat16* __restrict__ emb16, int Me, const __hip_bfloat16* __restrict__ Wt_kv,
    const float* __restrict__ bk, const float* __restrict__ bv,
    __hip_bfloat16* __restrict__ q16, __hip_bfloat16* __restrict__ k16,
    __hip_bfloat16* __restrict__ vt, int Mepad, int nbQ, int gxQ, int gxK) {
  __shared__ __align__(16) __hip_bfloat16 As[128][72];
  __shared__ __align__(16) __hip_bfloat16 Bs[64][72];
  int b = blockIdx.x;
  if (b < nbQ) {
    mgemm_body<2>(b % gxQ, b / gxQ, As, Bs, pool16, Mp, Wt_q, bq, nullptr,
                  q16, nullptr, nullptr, nullptr, 0);
  } else {
    b -= nbQ;
    mgemm_body<3>(b % gxK, b / gxK, As, Bs, emb16, Me, Wt_kv, bk, bv,
                  k16, vt, nullptr, nullptr, Mepad);
  }
}

// MFMA flash attention (round-10 measured best): double-buffered LDS K/V,
// ONE barrier/iter, register prefetch, exp2 softmax, interior-tile mask skip.
// Frozen: rounds 12 (8-wave), 13 (barrier-free L2), 14 (e-split) all
// null/negative — this structure is the floor (~41us) for this problem size.
__global__ __launch_bounds__(256) void attn_mfma_kernel(
    const __hip_bfloat16* __restrict__ qb, const __hip_bfloat16* __restrict__ kb,
    const __hip_bfloat16* __restrict__ vt, int Mepad,
    const int* __restrict__ pc, const int* __restrict__ eb,
    int Mp, int Me, __hip_bfloat16* __restrict__ ob) {
  __shared__ __align__(16) __hip_bfloat16 Ks[2][64][72];
  __shared__ __align__(16) __hip_bfloat16 Vs[2][64][72];
  __shared__ __align__(16) __hip_bfloat16 pl[4][16][72];
  __shared__ int sred[4][4];
  const int h = blockIdx.y;
  const int t = threadIdx.x;
  const int wv = t >> 6, lane = t & 63;
  const int lq = lane & 15, lg = lane >> 4;
  const int q0 = blockIdx.x * 64 + wv * 16;

  int lo[4], hi[4];
  #pragma unroll
  for (int r = 0; r < 4; ++r) {
    int q = q0 + lg * 4 + r;
    if (q < Mp) { int b = pc[4 * q]; lo[r] = eb[b]; hi[r] = eb[b + 1]; }
    else { lo[r] = 0x7fffffff; hi[r] = 0; }
  }
  int lomin = min(min(lo[0], lo[1]), min(lo[2], lo[3]));
  int lomax = max(max(lo[0], lo[1]), max(lo[2], lo[3]));
  int himin = min(min(hi[0], hi[1]), min(hi[2], hi[3]));
  int himax = max(max(hi[0], hi[1]), max(hi[2], hi[3]));
  #pragma unroll
  for (int off = 1; off < 64; off <<= 1) {
    lomin = min(lomin, __shfl_xor(lomin, off));
    lomax = max(lomax, __shfl_xor(lomax, off));
    himin = min(himin, __shfl_xor(himin, off));
    himax = max(himax, __shfl_xor(himax, off));
  }
  if (lane == 0) {
    sred[wv][0] = lomin; sred[wv][1] = lomax;
    sred[wv][2] = himin; sred[wv][3] = himax;
  }
  __syncthreads();
  lomin = min(min(sred[0][0], sred[1][0]), min(sred[2][0], sred[3][0]));
  lomax = max(max(sred[0][1], sred[1][1]), max(sred[2][1], sred[3][1]));
  himin = min(min(sred[0][2], sred[1][2]), min(sred[2][2], sred[3][2]));
  himax = max(max(sred[0][3], sred[1][3]), max(sred[2][3], sred[3][3]));

  int qrow = min(q0 + lq, Mp - 1);
  const __hip_bfloat16* qp = qb + (size_t)qrow * 512 + h * 64 + lg * 8;
  bf16x8 aq0 = *reinterpret_cast<const bf16x8*>(qp);
  bf16x8 aq1 = *reinterpret_cast<const bf16x8*>(qp + 32);

  const int str = t >> 2;
  const int stc = (t & 3) * 16;
  const __hip_bfloat16* vrow = vt + (size_t)(h * 64 + str) * Mepad + stc;

  f32x4 zero = {0.f, 0.f, 0.f, 0.f};
  f32x4 oacc[4];
  oacc[0] = zero; oacc[1] = zero; oacc[2] = zero; oacc[3] = zero;

  bf16x8 k0, k1, v0, v1;
  auto load_tile = [&](int e0) {
    int er = e0 + str;
    k0 = zero8(); k1 = zero8();
    if (er < Me) {
      const __hip_bfloat16* kp = kb + (size_t)er * 512 + h * 64 + stc;
      k0 = *reinterpret_cast<const bf16x8*>(kp);
      k1 = *reinterpret_cast<const bf16x8*>(kp + 8);
    }
    v0 = *reinterpret_cast<const bf16x8*>(vrow + e0);
    v1 = *reinterpret_cast<const bf16x8*>(vrow + e0 + 8);
  };
  auto store_tile = [&](int nb) {
    *reinterpret_cast<bf16x8*>(&Ks[nb][str][stc]) = k0;
    *reinterpret_cast<bf16x8*>(&Ks[nb][str][stc + 8]) = k1;
    *reinterpret_cast<bf16x8*>(&Vs[nb][str][stc]) = v0;
    *reinterpret_cast<bf16x8*>(&Vs[nb][str][stc + 8]) = v1;
  };
  const int e0beg = lomin & ~63;
  load_tile(e0beg);
  store_tile(0);
  if (e0beg + 64 < himax) load_tile(e0beg + 64);

  int it = 0;
  for (int e0 = e0beg; e0 < himax; e0 += 64, ++it) {
    __syncthreads();
    const int cur = it & 1;
    if (e0 + 64 < himax) {
      store_tile(cur ^ 1);
      if (e0 + 128 < himax) load_tile(e0 + 128);
    }

    f32x4 sf[4];
    #pragma unroll
    for (int s = 0; s < 4; ++s) {
      bf16x8 bk0 = *reinterpret_cast<const bf16x8*>(&Ks[cur][s * 16 + lq][lg * 8]);
      bf16x8 bk1 = *reinterpret_cast<const bf16x8*>(&Ks[cur][s * 16 + lq][32 + lg * 8]);
      f32x4 z = zero;
      z = mfma16(aq0, bk0, z);
      z = mfma16(aq1, bk1, z);
      sf[s] = z;
    }
    const bool interior = (e0 >= lomax) && (e0 + 64 <= himin);
    if (interior) {
      #pragma unroll
      for (int s = 0; s < 4; ++s)
        #pragma unroll
        for (int r = 0; r < 4; ++r)
          pl[wv][lg * 4 + r][s * 16 + lq] = __float2bfloat16(exp2f(sf[s][r]));
    } else {
      #pragma unroll
      for (int s = 0; s < 4; ++s) {
        int e = e0 + s * 16 + lq;
        #pragma unroll
        for (int r = 0; r < 4; ++r) {
          bool m = (e >= lo[r]) && (e < hi[r]);
          float p = m ? exp2f(sf[s][r]) : 0.f;
          pl[wv][lg * 4 + r][s * 16 + lq] = __float2bfloat16(p);
        }
      }
    }
    asm volatile("s_waitcnt lgkmcnt(0)" ::: "memory");
    __builtin_amdgcn_sched_barrier(0);  // rule #18
    #pragma unroll
    for (int ks = 0; ks < 2; ++ks) {
      bf16x8 ap = *reinterpret_cast<const bf16x8*>(&pl[wv][lq][ks * 32 + lg * 8]);
      #pragma unroll
      for (int dt = 0; dt < 4; ++dt) {
        bf16x8 bv = *reinterpret_cast<const bf16x8*>(&Vs[cur][dt * 16 + lq][ks * 32 + lg * 8]);
        oacc[dt] = mfma16(ap, bv, oacc[dt]);
      }
    }
  }

  #pragma unroll
  for (int r = 0; r < 4; ++r) {
    float l = __shfl(oacc[3][r], (lane & 48));
    int q = q0 + lg * 4 + r;
    if (q < Mp && l > 0.f) {
      float inv = 1.0f / l;
      __hip_bfloat16* op = ob + (size_t)q * CDIM + h * HD;
      op[lq]      = __float2bfloat16(oacc[0][r] * inv);
      op[16 + lq] = __float2bfloat16(oacc[1][r] * inv);
      op[32 + lq] = __float2bfloat16(oacc[2][r] * inv);
    }
  }
}

__global__ void newf16_kernel(const float* __restrict__ feats, const float* __restrict__ o2,
                              const int* __restrict__ pinv, __hip_bfloat16* __restrict__ nf,
                              int N) {
  int v = blockIdx.x * 256 + threadIdx.x;
  if (v >= N * 48) return;
  int n = v / 48, c8 = (v - n * 48) * 8;
  const float* fp = feats + (size_t)n * CDIM + c8;
  const float* op = o2 + (size_t)pinv[n] * CDIM + c8;
  float4 a0 = *reinterpret_cast<const float4*>(fp);
  float4 a1 = *reinterpret_cast<const float4*>(fp + 4);
  float4 b0 = *reinterpret_cast<const float4*>(op);
  float4 b1 = *reinterpret_cast<const float4*>(op + 4);
  __hip_bfloat16 tmp[8] = {
    __float2bfloat16(a0.x + b0.x), __float2bfloat16(a0.y + b0.y),
    __float2bfloat16(a0.z + b0.z), __float2bfloat16(a0.w + b0.w),
    __float2bfloat16(a1.x + b1.x), __float2bfloat16(a1.y + b1.y),
    __float2bfloat16(a1.z + b1.z), __float2bfloat16(a1.w + b1.w)};
  *reinterpret_cast<bf16x8*>(nf + (size_t)v * 8) = *reinterpret_cast<const bf16x8*>(tmp);
}

// conv as MFMA GEMM: M=N rows, 32 cols, K split by tap groups (9 x 3 taps).
__global__ __launch_bounds__(256) void mconv_kernel(
    const __hip_bfloat16* __restrict__ nf, const int* __restrict__ nbr,
    const __hip_bfloat16* __restrict__ Wct, float* __restrict__ outp, int N) {
  __shared__ __align__(16) __hip_bfloat16 As[128][72];
  __shared__ __align__(16) __hip_bfloat16 Bs[32][72];
  __shared__ int jrow[128];
  const int n0 = blockIdx.x * 128;
  const int kg = blockIdx.y;
  const int t = threadIdx.x;
  const int lane = t & 63, w = t >> 6;
  const int lq = lane & 15, lg = lane >> 4;
  f32x4 acc[2][2];
  acc[0][0] = (f32x4){0.f,0.f,0.f,0.f}; acc[0][1] = acc[0][0];
  acc[1][0] = acc[0][0]; acc[1][1] = acc[0][0];
  const int arow = t >> 3, acol = (t & 7) * 8;

  for (int kk = kg * 3; kk < kg * 3 + 3; ++kk) {
    __syncthreads();
    if (t < 128) {
      int n = n0 + t;
      jrow[t] = (n < N) ? nbr[(size_t)n * 27 + kk] : -1;
    }
    __syncthreads();
    for (int c0 = 0; c0 < CDIM; c0 += 64) {
      #pragma unroll
      for (int i = 0; i < 4; ++i) {
        int r = arow + i * 32;
        int j = jrow[r];
        bf16x8 val = zero8();
        if (j >= 0) val = *reinterpret_cast<const bf16x8*>(nf + (size_t)j * CDIM + c0 + acol);
        *reinterpret_cast<bf16x8*>(&As[r][acol]) = val;
      }
      {
        int r = t >> 3;
        bf16x8 val = *reinterpret_cast<const bf16x8*>(Wct + (size_t)r * CONVK + kk * CDIM + c0 + acol);
        *reinterpret_cast<bf16x8*>(&Bs[r][acol]) = val;
      }
      __syncthreads();
      #pragma unroll
      for (int ks = 0; ks < 2; ++ks) {
        bf16x8 af[2], bfv[2];
        #pragma unroll
        for (int fm = 0; fm < 2; ++fm)
          af[fm] = *reinterpret_cast<const bf16x8*>(&As[w * 32 + fm * 16 + lq][ks * 32 + lg * 8]);
        #pragma unroll
        for (int fn = 0; fn < 2; ++fn)
          bfv[fn] = *reinterpret_cast<const bf16x8*>(&Bs[fn * 16 + lq][ks * 32 + lg * 8]);
        #pragma unroll
        for (int fm = 0; fm < 2; ++fm)
          #pragma unroll
          for (int fn = 0; fn < 2; ++fn)
            acc[fm][fn] = mfma16(af[fm], bfv[fn], acc[fm][fn]);
      }
      __syncthreads();
    }
  }
  #pragma unroll
  for (int fm = 0; fm < 2; ++fm)
    #pragma unroll
    for (int j = 0; j < 4; ++j) {
      int r = n0 + w * 32 + fm * 16 + lg * 4 + j;
      if (r < N) {
        #pragma unroll
        for (int fn = 0; fn < 2; ++fn)
          outp[((size_t)kg * N + r) * OUTD + fn * 16 + lq] = acc[fm][fn][j];
      }
    }
}

__global__ void conv_reduce_kernel(const float* __restrict__ outp,
                                   const float* __restrict__ bc,
                                   float* __restrict__ out, int N) {
  int v = blockIdx.x * 256 + threadIdx.x;
  if (v >= N * OUTD) return;
  int oo = v & (OUTD - 1);
  float s = bc[oo];
  #pragma unroll
  for (int kg = 0; kg < 9; ++kg) s += outp[(size_t)kg * N * OUTD + v];
  out[v] = s;
}

extern "C" void kernel_launch(void* const* d_in, const int* in_sizes, int n_in,
                              void* d_out, int out_size, void* d_ws, size_t ws_size,
                              hipStream_t stream) {
  const float* feats  = (const float*)d_in[0];
  const float* W_pool = (const float*)d_in[1];
  const float* b_pool = (const float*)d_in[2];
  const float* W_emb  = (const float*)d_in[3];
  const float* b_emb  = (const float*)d_in[4];
  const float* Wq = (const float*)d_in[5];  const float* bq = (const float*)d_in[6];
  const float* Wk = (const float*)d_in[7];  const float* bk = (const float*)d_in[8];
  const float* Wv = (const float*)d_in[9];  const float* bv = (const float*)d_in[10];
  const float* Wo = (const float*)d_in[11]; const float* bo = (const float*)d_in[12];
  const float* Wc = (const float*)d_in[13]; const float* bc = (const float*)d_in[14];
  const int* pool_inv    = (const int*)d_in[15];
  const int* pool_coords = (const int*)d_in[16];
  const int* emb_inv     = (const int*)d_in[17];
  const int* emb_coords  = (const int*)d_in[18];
  const int* nbr         = (const int*)d_in[19];
  const int* bsz         = (const int*)d_in[20];
  int N  = in_sizes[0] / CDIM;
  int Mp = in_sizes[16] / 4;
  int Me = in_sizes[18] / 4;
  int Mepad = ((Me >> 6) + 2) << 6;

  char* wsb = (char*)d_ws;
  size_t off = 0;
  auto alloc = [&](size_t bytes) { void* p = wsb + off; off += (bytes + 255) & ~(size_t)255; return p; };
  unsigned* encA = (unsigned*)alloc((size_t)Mp * CDIM * 4);
  unsigned* encB = (unsigned*)alloc((size_t)Me * CDIM * 4);
  __hip_bfloat16* vt = (__hip_bfloat16*)alloc((size_t)512 * Mepad * 2);
  __hip_bfloat16* pool16  = (__hip_bfloat16*)alloc((size_t)Mp * CDIM * 2);
  __hip_bfloat16* emb16   = (__hip_bfloat16*)alloc((size_t)Me * CDIM * 2);
  __hip_bfloat16* feats16 = (__hip_bfloat16*)alloc((size_t)N * CDIM * 2);
  float* o2 = (float*)alloc((size_t)Mp * CDIM * 4 > (size_t)9 * N * OUTD * 4
                                ? (size_t)Mp * CDIM * 4 : (size_t)9 * N * OUTD * 4);
  __hip_bfloat16* Wt_pe = (__hip_bfloat16*)alloc((size_t)768 * CDIM * 2);
  __hip_bfloat16* Wt_kv = (__hip_bfloat16*)alloc((size_t)768 * CDIM * 2);
  __hip_bfloat16* Wt_q  = (__hip_bfloat16*)alloc((size_t)CDIM * CDIM * 2);
  __hip_bfloat16* Wt_o  = (__hip_bfloat16*)alloc((size_t)CDIM * CDIM * 2);
  __hip_bfloat16* Wct   = (__hip_bfloat16*)alloc((size_t)OUTD * CONVK * 2);
  int* smin = (int*)alloc(MAXB * 3 * 4);
  int* smax = (int*)alloc(MAXB * 3 * 4);
  int* eb   = (int*)alloc((MAXB + 1) * 4);

  __hip_bfloat16* q16  = (__hip_bfloat16*)encA;   // [Mp][512]
  __hip_bfloat16* k16  = (__hip_bfloat16*)encB;   // [Me][512]
  __hip_bfloat16* ob16 = pool16;                  // [Mp][384]
  __hip_bfloat16* newf16 = feats16;               // [N][384]
  float* outp = o2;                               // [9][N][32]

  init_small_kernel<<<1, 64, 0, stream>>>(smin, smax, eb);

  int nbF  = (N * 48 + 255) / 256;
  int nbW  = (CDIM * 48 + 255) / 256;
  int nbC  = (OUTD * (CONVK / 8) + 255) / 256;
  int nbZA = ((Mp * 96) + 255) / 256;
  int nbZB = ((Me * 96) + 255) / 256;
  int nbVt = ((512 * (Mepad >> 3)) + 255) / 256;
  int nbM  = (Mp + Me + 255) / 256;
  int nbE  = (Me + 255) / 256;
  prep_kernel<<<nbF + 6 * nbW + nbC + nbZA + nbZB + nbVt + nbM + nbE, 256, 0, stream>>>(
      feats, feats16, N, W_pool, W_emb, Wk, Wv, Wq, Wo,
      Wt_pe, Wt_kv, Wt_q, Wt_o, Wc, Wct, encA, encB, vt, Mepad,
      emb_coords, pool_coords, Mp, Me, bsz, smin, smax, eb,
      nbF, nbW, nbC, nbZA, nbZB, nbVt, nbM);

  mgemm0_kernel<<<dim3((N + 127) / 128, 12), 256, 0, stream>>>(
      feats16, N, Wt_pe, b_pool, b_emb, encA, encB, pool_inv, emb_inv);
  pe_kernel<<<((Mp + Me) * CDIM + 255) / 256, 256, 0, stream>>>(
      encA, encB, pool16, emb16, pool_coords, Mp, emb_coords, Me, smin, smax);

  // fused q + kv projections (pads zeroed in-kernel)
  {
    int gxQ = (Mp + 127) / 128, gxK = (Me + 127) / 128;
    int nbQ = gxQ * 6;
    qkv_kernel<<<nbQ + gxK * 12, 256, 0, stream>>>(
        pool16, Mp, Wt_q, bq, emb16, Me, Wt_kv, bk, bv,
        q16, k16, vt, Mepad, nbQ, gxQ, gxK);
  }

  attn_mfma_kernel<<<dim3((Mp + 63) / 64, NHEAD), 256, 0, stream>>>(
      q16, k16, vt, Mepad, pool_coords, eb, Mp, Me, ob16);

  mgemm1_kernel<<<dim3((Mp + 127) / 128, 6), 256, 0, stream>>>(
      ob16, Mp, Wt_o, bo, o2);

  newf16_kernel<<<(N * 48 + 255) / 256, 256, 0, stream>>>(feats, o2, pool_inv, newf16, N);

  mconv_kernel<<<dim3((N + 127) / 128, 9), 256, 0, stream>>>(newf16, nbr, Wct, outp, N);
  conv_reduce_kernel<<<(N * OUTD + 255) / 256, 256, 0, stream>>>(outp, bc, (float*)d_out, N);
}